// Round 8
// baseline (224.333 us; speedup 1.0000x reference)
//
#include <hip/hip_runtime.h>
#include <hip/hip_bf16.h>

#define NN 512      // nodes per graph
#define NE 8192     // edges per graph
#define NG 128      // graphs (B*G)
#define FH 128      // feature/hidden dim
#define NSEG 64     // edge-balanced node segments per graph
#define BN_EPS 1e-5f

typedef __attribute__((ext_vector_type(8))) short s8v;   // 8 bf16 = 4 VGPRs
typedef __attribute__((ext_vector_type(4))) float f4v;   // MFMA C/D

__device__ inline void f4acc(float4& a, const float4& b) {
    a.x += b.x; a.y += b.y; a.z += b.z; a.w += b.w;
}

__device__ inline unsigned short f2bf(float x) {   // RNE fp32 -> bf16 bits
    unsigned u = __float_as_uint(x);
    unsigned r = (u + 0x7fffu + ((u >> 16) & 1u)) >> 16;
    return (unsigned short)r;
}
__device__ inline float bf2f(unsigned short h) { return __uint_as_float(((unsigned)h) << 16); }

// ---------------- K1: degrees + norms + CSR (src+dst) + segments; blocks >= NG pack W ----------------
__global__ __launch_bounds__(1024) void k_build(const int* __restrict__ edges,
                                                float* __restrict__ rs_out,
                                                float* __restrict__ rs_in,
                                                int* __restrict__ row_ofs,
                                                int* __restrict__ csr_src,
                                                int* __restrict__ csr_dst,
                                                int* __restrict__ seg,
                                                const float* __restrict__ W0,
                                                const float* __restrict__ W1,
                                                unsigned short* __restrict__ WP) {
    int g = blockIdx.x;
    int tid = threadIdx.x;

    if (g >= NG) {
        // ---- weight packing blocks: bf16 hi/lo B-fragments ----
        int which = g - NG;
        const float* W = which ? W1 : W0;
        for (int task = tid; task < 2048; task += 1024) {
            int t = task >> 6;            // 0..31  (nt*4+kk)
            int lane = task & 63;
            int nt = t >> 2, kk = t & 3;
            int n = nt * 16 + (lane & 15);
            int k0 = kk * 32 + (lane >> 4) * 8;
            unsigned short* dh = WP + ((size_t)which * 2 + 0) * 16384 + ((size_t)t * 64 + lane) * 8;
            unsigned short* dl = WP + ((size_t)which * 2 + 1) * 16384 + ((size_t)t * 64 + lane) * 8;
#pragma unroll
            for (int j = 0; j < 8; j++) {
                float v = W[(size_t)(k0 + j) * FH + n];
                unsigned short h = f2bf(v);
                dh[j] = h;
                dl[j] = f2bf(v - bf2f(h));
            }
        }
        return;
    }

    const int* src = edges + (size_t)g * 2 * NE;
    const int* dst = src + NE;

    __shared__ int degO[NN], degI[NN];
    __shared__ int scanA[NN], scanB[NN];
    __shared__ int fill[NN];
    __shared__ int csr_lds[NE];          // 32 KB
    __shared__ int dst_lds[NE];          // 32 KB

    for (int i = tid; i < NN; i += 1024) { degO[i] = 0; degI[i] = 0; }
    __syncthreads();
    for (int u = tid; u < NE / 4; u += 1024) {
        int4 s = ((const int4*)src)[u];
        int4 d = ((const int4*)dst)[u];
        atomicAdd(&degO[s.x], 1); atomicAdd(&degO[s.y], 1);
        atomicAdd(&degO[s.z], 1); atomicAdd(&degO[s.w], 1);
        atomicAdd(&degI[d.x], 1); atomicAdd(&degI[d.y], 1);
        atomicAdd(&degI[d.z], 1); atomicAdd(&degI[d.w], 1);
    }
    __syncthreads();
    for (int i = tid; i < NN; i += 1024) {
        int dO = degO[i], dI = degI[i];
        rs_out[g * NN + i] = rsqrtf((float)max(dO, 1));
        rs_in [g * NN + i] = rsqrtf((float)max(dI, 1));
        scanA[i] = dI;
    }
    __syncthreads();
    int* sA = scanA; int* sB = scanB;
    for (int off = 1; off < NN; off <<= 1) {
        for (int i = tid; i < NN; i += 1024) {
            int v = sA[i];
            if (i >= off) v += sA[i - off];
            sB[i] = v;
        }
        __syncthreads();
        int* t = sA; sA = sB; sB = t;
    }
    for (int i = tid; i < NN; i += 1024) {
        int excl = (i == 0) ? 0 : sA[i - 1];
        fill[i] = excl;
        row_ofs[g * 513 + i] = excl;
    }
    if (tid == 0) row_ofs[g * 513 + NN] = sA[NN - 1];
    if (tid < NSEG) {
        int target = tid * (NE / NSEG);
        int lo = 0, hi = NN;
        while (lo < hi) {
            int mid = (lo + hi) >> 1;
            int ex = (mid == 0) ? 0 : sA[mid - 1];
            if (ex >= target) hi = mid; else lo = mid + 1;
        }
        seg[g * (NSEG + 1) + tid] = lo;
    }
    if (tid == 0) seg[g * (NSEG + 1) + NSEG] = NN;
    __syncthreads();
    for (int u = tid; u < NE / 4; u += 1024) {
        int4 s = ((const int4*)src)[u];
        int4 d = ((const int4*)dst)[u];
        int p0 = atomicAdd(&fill[d.x], 1); csr_lds[p0] = s.x; dst_lds[p0] = d.x;
        int p1 = atomicAdd(&fill[d.y], 1); csr_lds[p1] = s.y; dst_lds[p1] = d.y;
        int p2 = atomicAdd(&fill[d.z], 1); csr_lds[p2] = s.z; dst_lds[p2] = d.z;
        int p3 = atomicAdd(&fill[d.w], 1); csr_lds[p3] = s.w; dst_lds[p3] = d.w;
    }
    __syncthreads();
    for (int u = tid; u < NE / 4; u += 1024) {
        ((int4*)(csr_src + (size_t)g * NE))[u] = ((const int4*)csr_lds)[u];
        ((int4*)(csr_dst + (size_t)g * NE))[u] = ((const int4*)dst_lds)[u];
    }
    if (g == NG - 1 && tid < 16) {
        csr_src[(size_t)NG * NE + tid] = 0;
        csr_dst[(size_t)NG * NE + tid] = 0;
    }
}

// ---------------- K2/K4: Y = (X @ W) * rs_row  (bf16-split MFMA) ----------------
#define XPITCH 136
__global__ __launch_bounds__(256) void k_gemm(const float* __restrict__ X,
                                              const unsigned short* __restrict__ WPh,
                                              const unsigned short* __restrict__ WPl,
                                              const float* __restrict__ rs,
                                              float* __restrict__ Y) {
    __shared__ unsigned short xh[64 * XPITCH];   // 17 KB
    __shared__ unsigned short xl[64 * XPITCH];   // 17 KB
    int tid = threadIdx.x;
    size_t r0 = (size_t)blockIdx.x * 64;

    const float4* Xv = (const float4*)(X + r0 * FH);
#pragma unroll
    for (int i = 0; i < 8; i++) {
        int u = tid + i * 256;                 // 2048 float4 = 64x128
        int row = u >> 5, c4 = (u & 31) * 4;
        float4 v = Xv[u];
        int off = row * XPITCH + c4;
        unsigned short h0 = f2bf(v.x), h1 = f2bf(v.y), h2 = f2bf(v.z), h3 = f2bf(v.w);
        xh[off + 0] = h0; xh[off + 1] = h1; xh[off + 2] = h2; xh[off + 3] = h3;
        xl[off + 0] = f2bf(v.x - bf2f(h0));
        xl[off + 1] = f2bf(v.y - bf2f(h1));
        xl[off + 2] = f2bf(v.z - bf2f(h2));
        xl[off + 3] = f2bf(v.w - bf2f(h3));
    }
    __syncthreads();

    int lane = tid & 63, w = tid >> 6;
    int quad = lane >> 4, m = lane & 15;
    int arow = w * 16 + m;

    f4v acc[8];
#pragma unroll
    for (int nt = 0; nt < 8; nt++) acc[nt] = (f4v){0.f, 0.f, 0.f, 0.f};

#pragma unroll
    for (int kk = 0; kk < 4; kk++) {
        s8v ah = *(const s8v*)&xh[arow * XPITCH + kk * 32 + quad * 8];
        s8v al = *(const s8v*)&xl[arow * XPITCH + kk * 32 + quad * 8];
#pragma unroll
        for (int nt = 0; nt < 8; nt++) {
            s8v bh = *(const s8v*)(WPh + ((size_t)(nt * 4 + kk) * 64 + lane) * 8);
            s8v bl = *(const s8v*)(WPl + ((size_t)(nt * 4 + kk) * 64 + lane) * 8);
            acc[nt] = __builtin_amdgcn_mfma_f32_16x16x32_bf16(ah, bh, acc[nt], 0, 0, 0);
            acc[nt] = __builtin_amdgcn_mfma_f32_16x16x32_bf16(al, bh, acc[nt], 0, 0, 0);
            acc[nt] = __builtin_amdgcn_mfma_f32_16x16x32_bf16(ah, bl, acc[nt], 0, 0, 0);
        }
    }

    int orow = w * 16 + quad * 4;
    float4 rsv = *(const float4*)(rs + r0 + orow);
#pragma unroll
    for (int nt = 0; nt < 8; nt++) {
        Y[(r0 + orow + 0) * FH + nt * 16 + m] = acc[nt][0] * rsv.x;
        Y[(r0 + orow + 1) * FH + nt * 16 + m] = acc[nt][1] * rsv.y;
        Y[(r0 + orow + 2) * FH + nt * 16 + m] = acc[nt][2] * rsv.z;
        Y[(r0 + orow + 3) * FH + nt * 16 + m] = acc[nt][3] * rsv.w;
    }
}

// ---------------- K3: L2-direct flat-quad gather, full 128 features ----------------
// Block=(graph, sb). 8 groups x 32 lanes; group walks segment sb*8+grp; lane owns
// one float4 of the row. Y rows read from L2 (same-XCD via g%8 round-robin).
// Pipeline: meta 2 quads ahead, Y data 1 quad ahead.
__global__ __launch_bounds__(256) void k_gather(const float* __restrict__ Y,
                                                const int* __restrict__ row_ofs,
                                                const int* __restrict__ csr_src,
                                                const int* __restrict__ csr_dst,
                                                const int* __restrict__ seg,
                                                const float* __restrict__ rs_in,
                                                const float* __restrict__ bias,
                                                float* __restrict__ H) {
    int g  = blockIdx.x;
    int sb = blockIdx.y;   // 0..7
    int tid = threadIdx.x;
    int lane = tid & 31;
    int grp  = tid >> 5;   // 0..7

    __shared__ float rsin_s[NN];   // 2 KB
    for (int i = tid; i < NN; i += 256) rsin_s[i] = rs_in[g * NN + i];
    __syncthreads();

    int sidx = sb * 8 + grp;
    int d0 = seg[g * (NSEG + 1) + sidx], d1 = seg[g * (NSEG + 1) + sidx + 1];
    if (d0 >= d1) return;   // no barriers after this point

    const int* ro = row_ofs + g * 513;
    const float4* Yv = (const float4*)(Y + (size_t)g * NN * FH);
    const int* cs = csr_src + (size_t)g * NE;
    const int* cd = csr_dst + (size_t)g * NE;
    int e0 = ro[d0], eEnd = ro[d1];
    float4 bv = ((const float4*)bias)[lane];
    float4 rb;
    rb.x = fmaxf(bv.x, 0.f); rb.y = fmaxf(bv.y, 0.f);
    rb.z = fmaxf(bv.z, 0.f); rb.w = fmaxf(bv.w, 0.f);
    float* Hg = H + (size_t)g * NN * FH + lane * 4;

    int d = d0;
    float4 acc = make_float4(0.f, 0.f, 0.f, 0.f);
    int e = e0 & ~3;
    int4 S0 = *(const int4*)(cs + e),     D0 = *(const int4*)(cd + e);
    int4 S1 = *(const int4*)(cs + e + 4), D1 = *(const int4*)(cd + e + 4);
    float4 y0 = Yv[S0.x * 32 + lane];
    float4 y1 = Yv[S0.y * 32 + lane];
    float4 y2 = Yv[S0.z * 32 + lane];
    float4 y3 = Yv[S0.w * 32 + lane];
    for (; e < eEnd; e += 4) {
        int4 S2 = *(const int4*)(cs + e + 8);   // padded: always safe
        int4 D2 = *(const int4*)(cd + e + 8);
        float4 z0 = Yv[S1.x * 32 + lane];
        float4 z1 = Yv[S1.y * 32 + lane];
        float4 z2 = Yv[S1.z * 32 + lane];
        float4 z3 = Yv[S1.w * 32 + lane];
#define STEP(J, DJ, YJ)                                                     \
        {                                                                   \
            int idx = e + (J);                                              \
            bool valid = (idx >= e0) & (idx < eEnd);                        \
            if (valid && (DJ) != d) {                                       \
                float r = rsin_s[d];                                        \
                float4 h;                                                   \
                h.x = fmaxf(fmaf(r, acc.x, bv.x), 0.f);                     \
                h.y = fmaxf(fmaf(r, acc.y, bv.y), 0.f);                     \
                h.z = fmaxf(fmaf(r, acc.z, bv.z), 0.f);                     \
                h.w = fmaxf(fmaf(r, acc.w, bv.w), 0.f);                     \
                *(float4*)(Hg + (size_t)d * FH) = h;                        \
                for (int dd = d + 1; dd < (DJ); dd++)                       \
                    *(float4*)(Hg + (size_t)dd * FH) = rb;                  \
                d = (DJ);                                                   \
                acc = make_float4(0.f, 0.f, 0.f, 0.f);                      \
            }                                                               \
            if (valid) f4acc(acc, YJ);                                      \
        }
        STEP(0, D0.x, y0) STEP(1, D0.y, y1) STEP(2, D0.z, y2) STEP(3, D0.w, y3)
#undef STEP
        S0 = S1; D0 = D1; S1 = S2; D1 = D2;
        y0 = z0; y1 = z1; y2 = z2; y3 = z3;
    }
    {   // final flush + trailing empty rows
        float r = rsin_s[d];
        float4 h;
        h.x = fmaxf(fmaf(r, acc.x, bv.x), 0.f);
        h.y = fmaxf(fmaf(r, acc.y, bv.y), 0.f);
        h.z = fmaxf(fmaf(r, acc.z, bv.z), 0.f);
        h.w = fmaxf(fmaf(r, acc.w, bv.w), 0.f);
        *(float4*)(Hg + (size_t)d * FH) = h;
        for (int dd = d + 1; dd < d1; dd++)
            *(float4*)(Hg + (size_t)dd * FH) = rb;
    }
}

// ---------------- K5: L2-direct flat-quad gather2 + node-sum -> partial[g][sb] ----------------
__global__ __launch_bounds__(256) void k_gather_mean(const float* __restrict__ Y,
                                                     const int* __restrict__ row_ofs,
                                                     const int* __restrict__ csr_src,
                                                     const int* __restrict__ csr_dst,
                                                     const int* __restrict__ seg,
                                                     const float* __restrict__ rs_in,
                                                     const float* __restrict__ bias,
                                                     float* __restrict__ partial) {
    int g  = blockIdx.x;
    int sb = blockIdx.y;
    int tid = threadIdx.x;
    int lane = tid & 31;
    int grp  = tid >> 5;

    __shared__ float rsin_s[NN];     // 2 KB
    __shared__ float4 red[8][32];    // 4 KB
    for (int i = tid; i < NN; i += 256) rsin_s[i] = rs_in[g * NN + i];
    __syncthreads();

    int sidx = sb * 8 + grp;
    int d0 = seg[g * (NSEG + 1) + sidx], d1 = seg[g * (NSEG + 1) + sidx + 1];

    const int* ro = row_ofs + g * 513;
    const float4* Yv = (const float4*)(Y + (size_t)g * NN * FH);
    const int* cs = csr_src + (size_t)g * NE;
    const int* cd = csr_dst + (size_t)g * NE;
    float4 bv = ((const float4*)bias)[lane];
    float4 rb;
    rb.x = fmaxf(bv.x, 0.f); rb.y = fmaxf(bv.y, 0.f);
    rb.z = fmaxf(bv.z, 0.f); rb.w = fmaxf(bv.w, 0.f);

    float4 sum = make_float4(0.f, 0.f, 0.f, 0.f);
    if (d0 < d1) {
        int e0 = ro[d0], eEnd = ro[d1];
        int d = d0;
        float4 acc = make_float4(0.f, 0.f, 0.f, 0.f);
        int e = e0 & ~3;
        int4 S0 = *(const int4*)(cs + e),     D0 = *(const int4*)(cd + e);
        int4 S1 = *(const int4*)(cs + e + 4), D1 = *(const int4*)(cd + e + 4);
        float4 y0 = Yv[S0.x * 32 + lane];
        float4 y1 = Yv[S0.y * 32 + lane];
        float4 y2 = Yv[S0.z * 32 + lane];
        float4 y3 = Yv[S0.w * 32 + lane];
        for (; e < eEnd; e += 4) {
            int4 S2 = *(const int4*)(cs + e + 8);
            int4 D2 = *(const int4*)(cd + e + 8);
            float4 z0 = Yv[S1.x * 32 + lane];
            float4 z1 = Yv[S1.y * 32 + lane];
            float4 z2 = Yv[S1.z * 32 + lane];
            float4 z3 = Yv[S1.w * 32 + lane];
#define STEP(J, DJ, YJ)                                                     \
            {                                                               \
                int idx = e + (J);                                          \
                bool valid = (idx >= e0) & (idx < eEnd);                    \
                if (valid && (DJ) != d) {                                   \
                    float r = rsin_s[d];                                    \
                    sum.x += fmaxf(fmaf(r, acc.x, bv.x), 0.f);              \
                    sum.y += fmaxf(fmaf(r, acc.y, bv.y), 0.f);              \
                    sum.z += fmaxf(fmaf(r, acc.z, bv.z), 0.f);              \
                    sum.w += fmaxf(fmaf(r, acc.w, bv.w), 0.f);              \
                    float gf = (float)((DJ) - d - 1);                       \
                    sum.x += gf * rb.x; sum.y += gf * rb.y;                 \
                    sum.z += gf * rb.z; sum.w += gf * rb.w;                 \
                    d = (DJ);                                               \
                    acc = make_float4(0.f, 0.f, 0.f, 0.f);                  \
                }                                                           \
                if (valid) f4acc(acc, YJ);                                  \
            }
            STEP(0, D0.x, y0) STEP(1, D0.y, y1) STEP(2, D0.z, y2) STEP(3, D0.w, y3)
#undef STEP
            S0 = S1; D0 = D1; S1 = S2; D1 = D2;
            y0 = z0; y1 = z1; y2 = z2; y3 = z3;
        }
        {   // final flush + trailing empties
            float r = rsin_s[d];
            sum.x += fmaxf(fmaf(r, acc.x, bv.x), 0.f);
            sum.y += fmaxf(fmaf(r, acc.y, bv.y), 0.f);
            sum.z += fmaxf(fmaf(r, acc.z, bv.z), 0.f);
            sum.w += fmaxf(fmaf(r, acc.w, bv.w), 0.f);
            float gf = (float)(d1 - 1 - d);
            sum.x += gf * rb.x; sum.y += gf * rb.y;
            sum.z += gf * rb.z; sum.w += gf * rb.w;
        }
    }

    red[grp][lane] = sum;
    __syncthreads();
    if (grp == 0) {
        float4 t = red[0][lane];
#pragma unroll
        for (int j = 1; j < 8; j++) f4acc(t, red[j][lane]);
        *(float4*)(partial + (((size_t)g * 8 + sb) * FH) + lane * 4) = t;
    }
}

// ---------------- K6: z = (sum partials)/512 @ Wt + bt; BN eval; relu ----------------
__global__ __launch_bounds__(128) void k_head(const float* __restrict__ partial,
                                              const float* __restrict__ Wt,
                                              const float* __restrict__ bt,
                                              const float* __restrict__ gamma,
                                              const float* __restrict__ beta,
                                              const float* __restrict__ rmean,
                                              const float* __restrict__ rvar,
                                              float* __restrict__ out) {
    int g = blockIdx.x;
    int j = threadIdx.x;
    __shared__ float e[FH];
    float acc8 = 0.f;
#pragma unroll
    for (int q = 0; q < 8; q++) acc8 += partial[((size_t)g * 8 + q) * FH + j];
    e[j] = acc8 * (1.0f / (float)NN);
    __syncthreads();
    float acc = bt[j];
#pragma unroll 8
    for (int k = 0; k < FH; k++) acc += e[k] * Wt[(size_t)k * FH + j];
    float z = gamma[j] * (acc - rmean[j]) * rsqrtf(rvar[j] + BN_EPS) + beta[j];
    out[g * FH + j] = fmaxf(z, 0.f);
}

extern "C" void kernel_launch(void* const* d_in, const int* in_sizes, int n_in,
                              void* d_out, int out_size, void* d_ws, size_t ws_size,
                              hipStream_t stream) {
    const float* feats = (const float*)d_in[0];
    const int*   edges = (const int*)d_in[1];
    const float* W0    = (const float*)d_in[2];
    const float* b0    = (const float*)d_in[3];
    const float* W1    = (const float*)d_in[4];
    const float* b1    = (const float*)d_in[5];
    const float* Wt    = (const float*)d_in[6];
    const float* bt    = (const float*)d_in[7];
    const float* gamma = (const float*)d_in[8];
    const float* beta  = (const float*)d_in[9];
    const float* rmean = (const float*)d_in[10];
    const float* rvar  = (const float*)d_in[11];
    float* out = (float*)d_out;

    // workspace layout
    char* w = (char*)d_ws;
    float* rs_out  = (float*)w;   w += sizeof(float) * NG * NN;
    float* rs_in   = (float*)w;   w += sizeof(float) * NG * NN;
    int*   row_ofs = (int*)w;     w += sizeof(int) * NG * 520;
    int*   seg     = (int*)w;     w += sizeof(int) * NG * (NSEG + 1) + 64;
    int*   csr_src = (int*)w;     w += sizeof(int) * ((size_t)NG * NE + 16);
    int*   csr_dst = (int*)w;     w += sizeof(int) * ((size_t)NG * NE + 16);
    unsigned short* WP = (unsigned short*)w;  w += sizeof(unsigned short) * 4 * 16384; // 128 KB
    float* Y       = (float*)w;   w += sizeof(float) * (size_t)NG * NN * FH;
    float* H1      = (float*)w;   w += sizeof(float) * (size_t)NG * NN * FH;
    float* partial = (float*)w;   w += sizeof(float) * NG * 8 * FH;

    unsigned short* WPh0 = WP;
    unsigned short* WPl0 = WP + 16384;
    unsigned short* WPh1 = WP + 32768;
    unsigned short* WPl1 = WP + 49152;

    // K1: build norms + CSR + segments; 2 extra blocks pack W0/W1
    k_build<<<NG + 2, 1024, 0, stream>>>(edges, rs_out, rs_in, row_ofs, csr_src, csr_dst, seg,
                                         W0, W1, WP);

    k_gemm<<<(NG * NN) / 64, 256, 0, stream>>>(feats, WPh0, WPl0, rs_out, Y);

    k_gather<<<dim3(NG, 8), 256, 0, stream>>>(Y, row_ofs, csr_src, csr_dst, seg, rs_in, b0, H1);

    k_gemm<<<(NG * NN) / 64, 256, 0, stream>>>(H1, WPh1, WPl1, rs_out, Y);

    k_gather_mean<<<dim3(NG, 8), 256, 0, stream>>>(Y, row_ofs, csr_src, csr_dst, seg, rs_in, b1, partial);

    k_head<<<NG, 128, 0, stream>>>(partial, Wt, bt, gamma, beta, rmean, rvar, out);

    (void)in_sizes; (void)n_in; (void)out_size; (void)ws_size;
}

// Round 10
// 222.953 us; speedup vs baseline: 1.0062x; 1.0062x over previous
//
#include <hip/hip_runtime.h>
#include <hip/hip_bf16.h>

#define NN 512      // nodes per graph
#define NE 8192     // edges per graph
#define NG 128      // graphs (B*G)
#define FH 128      // feature/hidden dim
#define NSEG 64     // edge-balanced node segments per graph
#define BN_EPS 1e-5f

typedef __attribute__((ext_vector_type(8))) short s8v;   // 8 bf16 = 4 VGPRs
typedef __attribute__((ext_vector_type(4))) float f4v;   // MFMA C/D + native float4 for NT stores

__device__ inline void f4acc(float4& a, const float4& b) {
    a.x += b.x; a.y += b.y; a.z += b.z; a.w += b.w;
}

__device__ inline f4v to_f4v(const float4& v) { return (f4v){v.x, v.y, v.z, v.w}; }

__device__ inline unsigned short f2bf(float x) {   // RNE fp32 -> bf16 bits
    unsigned u = __float_as_uint(x);
    unsigned r = (u + 0x7fffu + ((u >> 16) & 1u)) >> 16;
    return (unsigned short)r;
}
__device__ inline float bf2f(unsigned short h) { return __uint_as_float(((unsigned)h) << 16); }

// ---------------- K1: degrees + norms + CSR (src+dst) + segments; blocks >= NG pack W ----------------
__global__ __launch_bounds__(1024) void k_build(const int* __restrict__ edges,
                                                float* __restrict__ rs_out,
                                                float* __restrict__ rs_in,
                                                int* __restrict__ row_ofs,
                                                int* __restrict__ csr_src,
                                                int* __restrict__ csr_dst,
                                                int* __restrict__ seg,
                                                const float* __restrict__ W0,
                                                const float* __restrict__ W1,
                                                unsigned short* __restrict__ WP) {
    int g = blockIdx.x;
    int tid = threadIdx.x;

    if (g >= NG) {
        // ---- weight packing blocks: bf16 hi/lo B-fragments ----
        int which = g - NG;
        const float* W = which ? W1 : W0;
        for (int task = tid; task < 2048; task += 1024) {
            int t = task >> 6;            // 0..31  (nt*4+kk)
            int lane = task & 63;
            int nt = t >> 2, kk = t & 3;
            int n = nt * 16 + (lane & 15);
            int k0 = kk * 32 + (lane >> 4) * 8;
            unsigned short* dh = WP + ((size_t)which * 2 + 0) * 16384 + ((size_t)t * 64 + lane) * 8;
            unsigned short* dl = WP + ((size_t)which * 2 + 1) * 16384 + ((size_t)t * 64 + lane) * 8;
#pragma unroll
            for (int j = 0; j < 8; j++) {
                float v = W[(size_t)(k0 + j) * FH + n];
                unsigned short h = f2bf(v);
                dh[j] = h;
                dl[j] = f2bf(v - bf2f(h));
            }
        }
        return;
    }

    const int* src = edges + (size_t)g * 2 * NE;
    const int* dst = src + NE;

    __shared__ int degO[NN], degI[NN];
    __shared__ int scanA[NN], scanB[NN];
    __shared__ int fill[NN];
    __shared__ int csr_lds[NE];          // 32 KB
    __shared__ int dst_lds[NE];          // 32 KB

    for (int i = tid; i < NN; i += 1024) { degO[i] = 0; degI[i] = 0; }
    __syncthreads();
    for (int u = tid; u < NE / 4; u += 1024) {
        int4 s = ((const int4*)src)[u];
        int4 d = ((const int4*)dst)[u];
        atomicAdd(&degO[s.x], 1); atomicAdd(&degO[s.y], 1);
        atomicAdd(&degO[s.z], 1); atomicAdd(&degO[s.w], 1);
        atomicAdd(&degI[d.x], 1); atomicAdd(&degI[d.y], 1);
        atomicAdd(&degI[d.z], 1); atomicAdd(&degI[d.w], 1);
    }
    __syncthreads();
    for (int i = tid; i < NN; i += 1024) {
        int dO = degO[i], dI = degI[i];
        rs_out[g * NN + i] = rsqrtf((float)max(dO, 1));
        rs_in [g * NN + i] = rsqrtf((float)max(dI, 1));
        scanA[i] = dI;
    }
    __syncthreads();
    int* sA = scanA; int* sB = scanB;
    for (int off = 1; off < NN; off <<= 1) {
        for (int i = tid; i < NN; i += 1024) {
            int v = sA[i];
            if (i >= off) v += sA[i - off];
            sB[i] = v;
        }
        __syncthreads();
        int* t = sA; sA = sB; sB = t;
    }
    for (int i = tid; i < NN; i += 1024) {
        int excl = (i == 0) ? 0 : sA[i - 1];
        fill[i] = excl;
        row_ofs[g * 513 + i] = excl;
    }
    if (tid == 0) row_ofs[g * 513 + NN] = sA[NN - 1];
    if (tid < NSEG) {
        int target = tid * (NE / NSEG);
        int lo = 0, hi = NN;
        while (lo < hi) {
            int mid = (lo + hi) >> 1;
            int ex = (mid == 0) ? 0 : sA[mid - 1];
            if (ex >= target) hi = mid; else lo = mid + 1;
        }
        seg[g * (NSEG + 1) + tid] = lo;
    }
    if (tid == 0) seg[g * (NSEG + 1) + NSEG] = NN;
    __syncthreads();
    for (int u = tid; u < NE / 4; u += 1024) {
        int4 s = ((const int4*)src)[u];
        int4 d = ((const int4*)dst)[u];
        int p0 = atomicAdd(&fill[d.x], 1); csr_lds[p0] = s.x; dst_lds[p0] = d.x;
        int p1 = atomicAdd(&fill[d.y], 1); csr_lds[p1] = s.y; dst_lds[p1] = d.y;
        int p2 = atomicAdd(&fill[d.z], 1); csr_lds[p2] = s.z; dst_lds[p2] = d.z;
        int p3 = atomicAdd(&fill[d.w], 1); csr_lds[p3] = s.w; dst_lds[p3] = d.w;
    }
    __syncthreads();
    for (int u = tid; u < NE / 4; u += 1024) {
        ((int4*)(csr_src + (size_t)g * NE))[u] = ((const int4*)csr_lds)[u];
        ((int4*)(csr_dst + (size_t)g * NE))[u] = ((const int4*)dst_lds)[u];
    }
    if (g == NG - 1 && tid < 16) {
        csr_src[(size_t)NG * NE + tid] = 0;
        csr_dst[(size_t)NG * NE + tid] = 0;
    }
}

// ---------------- K2/K4: Y = (X @ W) * rs_row  (bf16-split MFMA) ----------------
// Grid dim3(NG, 8): x = graph, y = 64-row slab. Linear id = x + 128*y -> XCD = x%8,
// so graph g's Y is produced on XCD g%8 — same XCD the gathers read it on.
#define XPITCH 136
__global__ __launch_bounds__(256) void k_gemm(const float* __restrict__ X,
                                              const unsigned short* __restrict__ WPh,
                                              const unsigned short* __restrict__ WPl,
                                              const float* __restrict__ rs,
                                              float* __restrict__ Y) {
    __shared__ unsigned short xh[64 * XPITCH];   // 17 KB
    __shared__ unsigned short xl[64 * XPITCH];   // 17 KB
    int tid = threadIdx.x;
    size_t r0 = (size_t)blockIdx.x * NN + (size_t)blockIdx.y * 64;

    const float4* Xv = (const float4*)(X + r0 * FH);
#pragma unroll
    for (int i = 0; i < 8; i++) {
        int u = tid + i * 256;                 // 2048 float4 = 64x128
        int row = u >> 5, c4 = (u & 31) * 4;
        float4 v = Xv[u];
        int off = row * XPITCH + c4;
        unsigned short h0 = f2bf(v.x), h1 = f2bf(v.y), h2 = f2bf(v.z), h3 = f2bf(v.w);
        xh[off + 0] = h0; xh[off + 1] = h1; xh[off + 2] = h2; xh[off + 3] = h3;
        xl[off + 0] = f2bf(v.x - bf2f(h0));
        xl[off + 1] = f2bf(v.y - bf2f(h1));
        xl[off + 2] = f2bf(v.z - bf2f(h2));
        xl[off + 3] = f2bf(v.w - bf2f(h3));
    }
    __syncthreads();

    int lane = tid & 63, w = tid >> 6;
    int quad = lane >> 4, m = lane & 15;
    int arow = w * 16 + m;

    f4v acc[8];
#pragma unroll
    for (int nt = 0; nt < 8; nt++) acc[nt] = (f4v){0.f, 0.f, 0.f, 0.f};

#pragma unroll
    for (int kk = 0; kk < 4; kk++) {
        s8v ah = *(const s8v*)&xh[arow * XPITCH + kk * 32 + quad * 8];
        s8v al = *(const s8v*)&xl[arow * XPITCH + kk * 32 + quad * 8];
#pragma unroll
        for (int nt = 0; nt < 8; nt++) {
            s8v bh = *(const s8v*)(WPh + ((size_t)(nt * 4 + kk) * 64 + lane) * 8);
            s8v bl = *(const s8v*)(WPl + ((size_t)(nt * 4 + kk) * 64 + lane) * 8);
            acc[nt] = __builtin_amdgcn_mfma_f32_16x16x32_bf16(ah, bh, acc[nt], 0, 0, 0);
            acc[nt] = __builtin_amdgcn_mfma_f32_16x16x32_bf16(al, bh, acc[nt], 0, 0, 0);
            acc[nt] = __builtin_amdgcn_mfma_f32_16x16x32_bf16(ah, bl, acc[nt], 0, 0, 0);
        }
    }

    int orow = w * 16 + quad * 4;
    float4 rsv = *(const float4*)(rs + r0 + orow);
#pragma unroll
    for (int nt = 0; nt < 8; nt++) {
        Y[(r0 + orow + 0) * FH + nt * 16 + m] = acc[nt][0] * rsv.x;
        Y[(r0 + orow + 1) * FH + nt * 16 + m] = acc[nt][1] * rsv.y;
        Y[(r0 + orow + 2) * FH + nt * 16 + m] = acc[nt][2] * rsv.z;
        Y[(r0 + orow + 3) * FH + nt * 16 + m] = acc[nt][3] * rsv.w;
    }
}

// ---------------- K3: L2-direct flat-quad gather, full 128 features ----------------
// Block=(graph, sb), XCD = g%8 (same as gemm's Y). H stores are non-temporal:
// no write-allocate fetch, no L2 pollution of Y.
__global__ __launch_bounds__(256) void k_gather(const float* __restrict__ Y,
                                                const int* __restrict__ row_ofs,
                                                const int* __restrict__ csr_src,
                                                const int* __restrict__ csr_dst,
                                                const int* __restrict__ seg,
                                                const float* __restrict__ rs_in,
                                                const float* __restrict__ bias,
                                                float* __restrict__ H) {
    int g  = blockIdx.x;
    int sb = blockIdx.y;   // 0..7
    int tid = threadIdx.x;
    int lane = tid & 31;
    int grp  = tid >> 5;   // 0..7

    __shared__ float rsin_s[NN];   // 2 KB
    for (int i = tid; i < NN; i += 256) rsin_s[i] = rs_in[g * NN + i];
    __syncthreads();

    int sidx = sb * 8 + grp;
    int d0 = seg[g * (NSEG + 1) + sidx], d1 = seg[g * (NSEG + 1) + sidx + 1];
    if (d0 >= d1) return;   // no barriers after this point

    const int* ro = row_ofs + g * 513;
    const float4* Yv = (const float4*)(Y + (size_t)g * NN * FH);
    const int* cs = csr_src + (size_t)g * NE;
    const int* cd = csr_dst + (size_t)g * NE;
    int e0 = ro[d0], eEnd = ro[d1];
    float4 bv = ((const float4*)bias)[lane];
    float4 rb;
    rb.x = fmaxf(bv.x, 0.f); rb.y = fmaxf(bv.y, 0.f);
    rb.z = fmaxf(bv.z, 0.f); rb.w = fmaxf(bv.w, 0.f);
    f4v rbn = to_f4v(rb);
    f4v* Hg = (f4v*)(H + (size_t)g * NN * FH) + lane;

    int d = d0;
    float4 acc = make_float4(0.f, 0.f, 0.f, 0.f);
    int e = e0 & ~3;
    int4 S0 = *(const int4*)(cs + e),     D0 = *(const int4*)(cd + e);
    int4 S1 = *(const int4*)(cs + e + 4), D1 = *(const int4*)(cd + e + 4);
    float4 y0 = Yv[S0.x * 32 + lane];
    float4 y1 = Yv[S0.y * 32 + lane];
    float4 y2 = Yv[S0.z * 32 + lane];
    float4 y3 = Yv[S0.w * 32 + lane];
    for (; e < eEnd; e += 4) {
        int4 S2 = *(const int4*)(cs + e + 8);   // padded: always safe
        int4 D2 = *(const int4*)(cd + e + 8);
        float4 z0 = Yv[S1.x * 32 + lane];
        float4 z1 = Yv[S1.y * 32 + lane];
        float4 z2 = Yv[S1.z * 32 + lane];
        float4 z3 = Yv[S1.w * 32 + lane];
#define STEP(J, DJ, YJ)                                                     \
        {                                                                   \
            int idx = e + (J);                                              \
            bool valid = (idx >= e0) & (idx < eEnd);                        \
            if (valid && (DJ) != d) {                                       \
                float r = rsin_s[d];                                        \
                f4v h;                                                      \
                h.x = fmaxf(fmaf(r, acc.x, bv.x), 0.f);                     \
                h.y = fmaxf(fmaf(r, acc.y, bv.y), 0.f);                     \
                h.z = fmaxf(fmaf(r, acc.z, bv.z), 0.f);                     \
                h.w = fmaxf(fmaf(r, acc.w, bv.w), 0.f);                     \
                __builtin_nontemporal_store(h, Hg + (size_t)d * 32);        \
                for (int dd = d + 1; dd < (DJ); dd++)                       \
                    __builtin_nontemporal_store(rbn, Hg + (size_t)dd * 32); \
                d = (DJ);                                                   \
                acc = make_float4(0.f, 0.f, 0.f, 0.f);                      \
            }                                                               \
            if (valid) f4acc(acc, YJ);                                      \
        }
        STEP(0, D0.x, y0) STEP(1, D0.y, y1) STEP(2, D0.z, y2) STEP(3, D0.w, y3)
#undef STEP
        S0 = S1; D0 = D1; S1 = S2; D1 = D2;
        y0 = z0; y1 = z1; y2 = z2; y3 = z3;
    }
    {   // final flush + trailing empty rows
        float r = rsin_s[d];
        f4v h;
        h.x = fmaxf(fmaf(r, acc.x, bv.x), 0.f);
        h.y = fmaxf(fmaf(r, acc.y, bv.y), 0.f);
        h.z = fmaxf(fmaf(r, acc.z, bv.z), 0.f);
        h.w = fmaxf(fmaf(r, acc.w, bv.w), 0.f);
        __builtin_nontemporal_store(h, Hg + (size_t)d * 32);
        for (int dd = d + 1; dd < d1; dd++)
            __builtin_nontemporal_store(rbn, Hg + (size_t)dd * 32);
    }
}

// ---------------- K5: L2-direct flat-quad gather2 + node-sum -> partial[g][sb] ----------------
__global__ __launch_bounds__(256) void k_gather_mean(const float* __restrict__ Y,
                                                     const int* __restrict__ row_ofs,
                                                     const int* __restrict__ csr_src,
                                                     const int* __restrict__ csr_dst,
                                                     const int* __restrict__ seg,
                                                     const float* __restrict__ rs_in,
                                                     const float* __restrict__ bias,
                                                     float* __restrict__ partial) {
    int g  = blockIdx.x;
    int sb = blockIdx.y;
    int tid = threadIdx.x;
    int lane = tid & 31;
    int grp  = tid >> 5;

    __shared__ float rsin_s[NN];     // 2 KB
    __shared__ float4 red[8][32];    // 4 KB
    for (int i = tid; i < NN; i += 256) rsin_s[i] = rs_in[g * NN + i];
    __syncthreads();

    int sidx = sb * 8 + grp;
    int d0 = seg[g * (NSEG + 1) + sidx], d1 = seg[g * (NSEG + 1) + sidx + 1];

    const int* ro = row_ofs + g * 513;
    const float4* Yv = (const float4*)(Y + (size_t)g * NN * FH);
    const int* cs = csr_src + (size_t)g * NE;
    const int* cd = csr_dst + (size_t)g * NE;
    float4 bv = ((const float4*)bias)[lane];
    float4 rb;
    rb.x = fmaxf(bv.x, 0.f); rb.y = fmaxf(bv.y, 0.f);
    rb.z = fmaxf(bv.z, 0.f); rb.w = fmaxf(bv.w, 0.f);

    float4 sum = make_float4(0.f, 0.f, 0.f, 0.f);
    if (d0 < d1) {
        int e0 = ro[d0], eEnd = ro[d1];
        int d = d0;
        float4 acc = make_float4(0.f, 0.f, 0.f, 0.f);
        int e = e0 & ~3;
        int4 S0 = *(const int4*)(cs + e),     D0 = *(const int4*)(cd + e);
        int4 S1 = *(const int4*)(cs + e + 4), D1 = *(const int4*)(cd + e + 4);
        float4 y0 = Yv[S0.x * 32 + lane];
        float4 y1 = Yv[S0.y * 32 + lane];
        float4 y2 = Yv[S0.z * 32 + lane];
        float4 y3 = Yv[S0.w * 32 + lane];
        for (; e < eEnd; e += 4) {
            int4 S2 = *(const int4*)(cs + e + 8);
            int4 D2 = *(const int4*)(cd + e + 8);
            float4 z0 = Yv[S1.x * 32 + lane];
            float4 z1 = Yv[S1.y * 32 + lane];
            float4 z2 = Yv[S1.z * 32 + lane];
            float4 z3 = Yv[S1.w * 32 + lane];
#define STEP(J, DJ, YJ)                                                     \
            {                                                               \
                int idx = e + (J);                                          \
                bool valid = (idx >= e0) & (idx < eEnd);                    \
                if (valid && (DJ) != d) {                                   \
                    float r = rsin_s[d];                                    \
                    sum.x += fmaxf(fmaf(r, acc.x, bv.x), 0.f);              \
                    sum.y += fmaxf(fmaf(r, acc.y, bv.y), 0.f);              \
                    sum.z += fmaxf(fmaf(r, acc.z, bv.z), 0.f);              \
                    sum.w += fmaxf(fmaf(r, acc.w, bv.w), 0.f);              \
                    float gf = (float)((DJ) - d - 1);                       \
                    sum.x += gf * rb.x; sum.y += gf * rb.y;                 \
                    sum.z += gf * rb.z; sum.w += gf * rb.w;                 \
                    d = (DJ);                                               \
                    acc = make_float4(0.f, 0.f, 0.f, 0.f);                  \
                }                                                           \
                if (valid) f4acc(acc, YJ);                                  \
            }
            STEP(0, D0.x, y0) STEP(1, D0.y, y1) STEP(2, D0.z, y2) STEP(3, D0.w, y3)
#undef STEP
            S0 = S1; D0 = D1; S1 = S2; D1 = D2;
            y0 = z0; y1 = z1; y2 = z2; y3 = z3;
        }
        {   // final flush + trailing empties
            float r = rsin_s[d];
            sum.x += fmaxf(fmaf(r, acc.x, bv.x), 0.f);
            sum.y += fmaxf(fmaf(r, acc.y, bv.y), 0.f);
            sum.z += fmaxf(fmaf(r, acc.z, bv.z), 0.f);
            sum.w += fmaxf(fmaf(r, acc.w, bv.w), 0.f);
            float gf = (float)(d1 - 1 - d);
            sum.x += gf * rb.x; sum.y += gf * rb.y;
            sum.z += gf * rb.z; sum.w += gf * rb.w;
        }
    }

    red[grp][lane] = sum;
    __syncthreads();
    if (grp == 0) {
        float4 t = red[0][lane];
#pragma unroll
        for (int j = 1; j < 8; j++) f4acc(t, red[j][lane]);
        *(float4*)(partial + (((size_t)g * 8 + sb) * FH) + lane * 4) = t;
    }
}

// ---------------- K6: z = (sum partials)/512 @ Wt + bt; BN eval; relu ----------------
__global__ __launch_bounds__(128) void k_head(const float* __restrict__ partial,
                                              const float* __restrict__ Wt,
                                              const float* __restrict__ bt,
                                              const float* __restrict__ gamma,
                                              const float* __restrict__ beta,
                                              const float* __restrict__ rmean,
                                              const float* __restrict__ rvar,
                                              float* __restrict__ out) {
    int g = blockIdx.x;
    int j = threadIdx.x;
    __shared__ float e[FH];
    float acc8 = 0.f;
#pragma unroll
    for (int q = 0; q < 8; q++) acc8 += partial[((size_t)g * 8 + q) * FH + j];
    e[j] = acc8 * (1.0f / (float)NN);
    __syncthreads();
    float acc = bt[j];
#pragma unroll 8
    for (int k = 0; k < FH; k++) acc += e[k] * Wt[(size_t)k * FH + j];
    float z = gamma[j] * (acc - rmean[j]) * rsqrtf(rvar[j] + BN_EPS) + beta[j];
    out[g * FH + j] = fmaxf(z, 0.f);
}

extern "C" void kernel_launch(void* const* d_in, const int* in_sizes, int n_in,
                              void* d_out, int out_size, void* d_ws, size_t ws_size,
                              hipStream_t stream) {
    const float* feats = (const float*)d_in[0];
    const int*   edges = (const int*)d_in[1];
    const float* W0    = (const float*)d_in[2];
    const float* b0    = (const float*)d_in[3];
    const float* W1    = (const float*)d_in[4];
    const float* b1    = (const float*)d_in[5];
    const float* Wt    = (const float*)d_in[6];
    const float* bt    = (const float*)d_in[7];
    const float* gamma = (const float*)d_in[8];
    const float* beta  = (const float*)d_in[9];
    const float* rmean = (const float*)d_in[10];
    const float* rvar  = (const float*)d_in[11];
    float* out = (float*)d_out;

    // workspace layout
    char* w = (char*)d_ws;
    float* rs_out  = (float*)w;   w += sizeof(float) * NG * NN;
    float* rs_in   = (float*)w;   w += sizeof(float) * NG * NN;
    int*   row_ofs = (int*)w;     w += sizeof(int) * NG * 520;
    int*   seg     = (int*)w;     w += sizeof(int) * NG * (NSEG + 1) + 64;
    int*   csr_src = (int*)w;     w += sizeof(int) * ((size_t)NG * NE + 16);
    int*   csr_dst = (int*)w;     w += sizeof(int) * ((size_t)NG * NE + 16);
    unsigned short* WP = (unsigned short*)w;  w += sizeof(unsigned short) * 4 * 16384; // 128 KB
    float* Y       = (float*)w;   w += sizeof(float) * (size_t)NG * NN * FH;
    float* H1      = (float*)w;   w += sizeof(float) * (size_t)NG * NN * FH;
    float* partial = (float*)w;   w += sizeof(float) * NG * 8 * FH;

    unsigned short* WPh0 = WP;
    unsigned short* WPl0 = WP + 16384;
    unsigned short* WPh1 = WP + 32768;
    unsigned short* WPl1 = WP + 49152;

    // K1: build norms + CSR + segments; 2 extra blocks pack W0/W1
    k_build<<<NG + 2, 1024, 0, stream>>>(edges, rs_out, rs_in, row_ofs, csr_src, csr_dst, seg,
                                         W0, W1, WP);

    // K2: x = graph, y = slab -> Y produced on XCD g%8
    k_gemm<<<dim3(NG, 8), 256, 0, stream>>>(feats, WPh0, WPl0, rs_out, Y);

    k_gather<<<dim3(NG, 8), 256, 0, stream>>>(Y, row_ofs, csr_src, csr_dst, seg, rs_in, b0, H1);

    k_gemm<<<dim3(NG, 8), 256, 0, stream>>>(H1, WPh1, WPl1, rs_out, Y);

    k_gather_mean<<<dim3(NG, 8), 256, 0, stream>>>(Y, row_ofs, csr_src, csr_dst, seg, rs_in, b1, partial);

    k_head<<<NG, 128, 0, stream>>>(partial, Wt, bt, gamma, beta, rmean, rvar, out);

    (void)in_sizes; (void)n_in; (void)out_size; (void)ws_size;
}

// Round 11
// 199.766 us; speedup vs baseline: 1.1230x; 1.1161x over previous
//
#include <hip/hip_runtime.h>
#include <hip/hip_bf16.h>

#define NN 512      // nodes per graph
#define NE 8192     // edges per graph
#define NG 128      // graphs (B*G)
#define FH 128      // feature/hidden dim
#define NSEG 64     // edge-balanced node segments per graph
#define BN_EPS 1e-5f

typedef __attribute__((ext_vector_type(8))) short s8v;            // 8 bf16 = 4 VGPRs
typedef __attribute__((ext_vector_type(4))) float f4v;            // MFMA C/D
typedef __attribute__((ext_vector_type(4))) unsigned short us4v;  // native ushort4 for NT stores

__device__ inline void f4acc(float4& a, const float4& b) {
    a.x += b.x; a.y += b.y; a.z += b.z; a.w += b.w;
}

__device__ inline unsigned short f2bf(float x) {   // RNE fp32 -> bf16 bits
    unsigned u = __float_as_uint(x);
    unsigned r = (u + 0x7fffu + ((u >> 16) & 1u)) >> 16;
    return (unsigned short)r;
}
__device__ inline float bf2f(unsigned short h) { return __uint_as_float(((unsigned)h) << 16); }
__device__ inline float4 bf4_to_f4(const ushort4& v) {
    return make_float4(bf2f(v.x), bf2f(v.y), bf2f(v.z), bf2f(v.w));
}

// ---------------- K1: degrees + norms + CSR (src+dst) + segments; blocks >= NG pack W ----------------
__global__ __launch_bounds__(1024) void k_build(const int* __restrict__ edges,
                                                float* __restrict__ rs_out,
                                                float* __restrict__ rs_in,
                                                int* __restrict__ row_ofs,
                                                int* __restrict__ csr_src,
                                                int* __restrict__ csr_dst,
                                                int* __restrict__ seg,
                                                const float* __restrict__ W0,
                                                const float* __restrict__ W1,
                                                unsigned short* __restrict__ WP) {
    int g = blockIdx.x;
    int tid = threadIdx.x;

    if (g >= NG) {
        // ---- weight packing blocks: bf16 hi/lo B-fragments ----
        int which = g - NG;
        const float* W = which ? W1 : W0;
        for (int task = tid; task < 2048; task += 1024) {
            int t = task >> 6;            // 0..31  (nt*4+kk)
            int lane = task & 63;
            int nt = t >> 2, kk = t & 3;
            int n = nt * 16 + (lane & 15);
            int k0 = kk * 32 + (lane >> 4) * 8;
            unsigned short* dh = WP + ((size_t)which * 2 + 0) * 16384 + ((size_t)t * 64 + lane) * 8;
            unsigned short* dl = WP + ((size_t)which * 2 + 1) * 16384 + ((size_t)t * 64 + lane) * 8;
#pragma unroll
            for (int j = 0; j < 8; j++) {
                float v = W[(size_t)(k0 + j) * FH + n];
                unsigned short h = f2bf(v);
                dh[j] = h;
                dl[j] = f2bf(v - bf2f(h));
            }
        }
        return;
    }

    const int* src = edges + (size_t)g * 2 * NE;
    const int* dst = src + NE;

    __shared__ int degO[NN], degI[NN];
    __shared__ int scanA[NN], scanB[NN];
    __shared__ int fill[NN];
    __shared__ int csr_lds[NE];          // 32 KB
    __shared__ int dst_lds[NE];          // 32 KB

    for (int i = tid; i < NN; i += 1024) { degO[i] = 0; degI[i] = 0; }
    __syncthreads();
    for (int u = tid; u < NE / 4; u += 1024) {
        int4 s = ((const int4*)src)[u];
        int4 d = ((const int4*)dst)[u];
        atomicAdd(&degO[s.x], 1); atomicAdd(&degO[s.y], 1);
        atomicAdd(&degO[s.z], 1); atomicAdd(&degO[s.w], 1);
        atomicAdd(&degI[d.x], 1); atomicAdd(&degI[d.y], 1);
        atomicAdd(&degI[d.z], 1); atomicAdd(&degI[d.w], 1);
    }
    __syncthreads();
    for (int i = tid; i < NN; i += 1024) {
        int dO = degO[i], dI = degI[i];
        rs_out[g * NN + i] = rsqrtf((float)max(dO, 1));
        rs_in [g * NN + i] = rsqrtf((float)max(dI, 1));
        scanA[i] = dI;
    }
    __syncthreads();
    int* sA = scanA; int* sB = scanB;
    for (int off = 1; off < NN; off <<= 1) {
        for (int i = tid; i < NN; i += 1024) {
            int v = sA[i];
            if (i >= off) v += sA[i - off];
            sB[i] = v;
        }
        __syncthreads();
        int* t = sA; sA = sB; sB = t;
    }
    for (int i = tid; i < NN; i += 1024) {
        int excl = (i == 0) ? 0 : sA[i - 1];
        fill[i] = excl;
        row_ofs[g * 513 + i] = excl;
    }
    if (tid == 0) row_ofs[g * 513 + NN] = sA[NN - 1];
    if (tid < NSEG) {
        int target = tid * (NE / NSEG);
        int lo = 0, hi = NN;
        while (lo < hi) {
            int mid = (lo + hi) >> 1;
            int ex = (mid == 0) ? 0 : sA[mid - 1];
            if (ex >= target) hi = mid; else lo = mid + 1;
        }
        seg[g * (NSEG + 1) + tid] = lo;
    }
    if (tid == 0) seg[g * (NSEG + 1) + NSEG] = NN;
    __syncthreads();
    for (int u = tid; u < NE / 4; u += 1024) {
        int4 s = ((const int4*)src)[u];
        int4 d = ((const int4*)dst)[u];
        int p0 = atomicAdd(&fill[d.x], 1); csr_lds[p0] = s.x; dst_lds[p0] = d.x;
        int p1 = atomicAdd(&fill[d.y], 1); csr_lds[p1] = s.y; dst_lds[p1] = d.y;
        int p2 = atomicAdd(&fill[d.z], 1); csr_lds[p2] = s.z; dst_lds[p2] = d.z;
        int p3 = atomicAdd(&fill[d.w], 1); csr_lds[p3] = s.w; dst_lds[p3] = d.w;
    }
    __syncthreads();
    for (int u = tid; u < NE / 4; u += 1024) {
        ((int4*)(csr_src + (size_t)g * NE))[u] = ((const int4*)csr_lds)[u];
        ((int4*)(csr_dst + (size_t)g * NE))[u] = ((const int4*)dst_lds)[u];
    }
    if (g == NG - 1 && tid < 16) {
        csr_src[(size_t)NG * NE + tid] = 0;
        csr_dst[(size_t)NG * NE + tid] = 0;
    }
}

// ---------------- K2: Yb(bf16) = (feats(fp32) @ W0) * rs  (hi/lo split, 3 MFMA) ----------------
// Grid dim3(NG, 8): x = graph, y = 64-row slab -> XCD = g%8.
#define XPITCH 136
__global__ __launch_bounds__(256) void k_gemm_f32(const float* __restrict__ X,
                                                  const unsigned short* __restrict__ WPh,
                                                  const unsigned short* __restrict__ WPl,
                                                  const float* __restrict__ rs,
                                                  unsigned short* __restrict__ Yb) {
    __shared__ unsigned short xh[64 * XPITCH];   // 17 KB
    __shared__ unsigned short xl[64 * XPITCH];   // 17 KB
    int tid = threadIdx.x;
    size_t r0 = (size_t)blockIdx.x * NN + (size_t)blockIdx.y * 64;

    const float4* Xv = (const float4*)(X + r0 * FH);
#pragma unroll
    for (int i = 0; i < 8; i++) {
        int u = tid + i * 256;                 // 2048 float4 = 64x128
        int row = u >> 5, c4 = (u & 31) * 4;
        float4 v = Xv[u];
        int off = row * XPITCH + c4;
        unsigned short h0 = f2bf(v.x), h1 = f2bf(v.y), h2 = f2bf(v.z), h3 = f2bf(v.w);
        xh[off + 0] = h0; xh[off + 1] = h1; xh[off + 2] = h2; xh[off + 3] = h3;
        xl[off + 0] = f2bf(v.x - bf2f(h0));
        xl[off + 1] = f2bf(v.y - bf2f(h1));
        xl[off + 2] = f2bf(v.z - bf2f(h2));
        xl[off + 3] = f2bf(v.w - bf2f(h3));
    }
    __syncthreads();

    int lane = tid & 63, w = tid >> 6;
    int quad = lane >> 4, m = lane & 15;
    int arow = w * 16 + m;

    f4v acc[8];
#pragma unroll
    for (int nt = 0; nt < 8; nt++) acc[nt] = (f4v){0.f, 0.f, 0.f, 0.f};

#pragma unroll
    for (int kk = 0; kk < 4; kk++) {
        s8v ah = *(const s8v*)&xh[arow * XPITCH + kk * 32 + quad * 8];
        s8v al = *(const s8v*)&xl[arow * XPITCH + kk * 32 + quad * 8];
#pragma unroll
        for (int nt = 0; nt < 8; nt++) {
            s8v bh = *(const s8v*)(WPh + ((size_t)(nt * 4 + kk) * 64 + lane) * 8);
            s8v bl = *(const s8v*)(WPl + ((size_t)(nt * 4 + kk) * 64 + lane) * 8);
            acc[nt] = __builtin_amdgcn_mfma_f32_16x16x32_bf16(ah, bh, acc[nt], 0, 0, 0);
            acc[nt] = __builtin_amdgcn_mfma_f32_16x16x32_bf16(al, bh, acc[nt], 0, 0, 0);
            acc[nt] = __builtin_amdgcn_mfma_f32_16x16x32_bf16(ah, bl, acc[nt], 0, 0, 0);
        }
    }

    int orow = w * 16 + quad * 4;
    float4 rsv = *(const float4*)(rs + r0 + orow);
#pragma unroll
    for (int nt = 0; nt < 8; nt++) {
        Yb[(r0 + orow + 0) * FH + nt * 16 + m] = f2bf(acc[nt][0] * rsv.x);
        Yb[(r0 + orow + 1) * FH + nt * 16 + m] = f2bf(acc[nt][1] * rsv.y);
        Yb[(r0 + orow + 2) * FH + nt * 16 + m] = f2bf(acc[nt][2] * rsv.z);
        Yb[(r0 + orow + 3) * FH + nt * 16 + m] = f2bf(acc[nt][3] * rsv.w);
    }
}

// ---------------- K4: Yb(bf16) = (H1(bf16) @ W1) * rs  (no X split, 2 MFMA) ----------------
__global__ __launch_bounds__(256) void k_gemm_bf16(const unsigned short* __restrict__ X,
                                                   const unsigned short* __restrict__ WPh,
                                                   const unsigned short* __restrict__ WPl,
                                                   const float* __restrict__ rs,
                                                   unsigned short* __restrict__ Yb) {
    __shared__ unsigned short xh[64 * XPITCH];   // 17 KB
    int tid = threadIdx.x;
    size_t r0 = (size_t)blockIdx.x * NN + (size_t)blockIdx.y * 64;

    const ushort4* Xv = (const ushort4*)(X + r0 * FH);
#pragma unroll
    for (int i = 0; i < 8; i++) {
        int u = tid + i * 256;                 // 2048 ushort4 = 64x128
        int row = u >> 5, c4 = (u & 31) * 4;
        ushort4 v = Xv[u];
        int off = row * XPITCH + c4;
        xh[off + 0] = v.x; xh[off + 1] = v.y; xh[off + 2] = v.z; xh[off + 3] = v.w;
    }
    __syncthreads();

    int lane = tid & 63, w = tid >> 6;
    int quad = lane >> 4, m = lane & 15;
    int arow = w * 16 + m;

    f4v acc[8];
#pragma unroll
    for (int nt = 0; nt < 8; nt++) acc[nt] = (f4v){0.f, 0.f, 0.f, 0.f};

#pragma unroll
    for (int kk = 0; kk < 4; kk++) {
        s8v ah = *(const s8v*)&xh[arow * XPITCH + kk * 32 + quad * 8];
#pragma unroll
        for (int nt = 0; nt < 8; nt++) {
            s8v bh = *(const s8v*)(WPh + ((size_t)(nt * 4 + kk) * 64 + lane) * 8);
            s8v bl = *(const s8v*)(WPl + ((size_t)(nt * 4 + kk) * 64 + lane) * 8);
            acc[nt] = __builtin_amdgcn_mfma_f32_16x16x32_bf16(ah, bh, acc[nt], 0, 0, 0);
            acc[nt] = __builtin_amdgcn_mfma_f32_16x16x32_bf16(ah, bl, acc[nt], 0, 0, 0);
        }
    }

    int orow = w * 16 + quad * 4;
    float4 rsv = *(const float4*)(rs + r0 + orow);
#pragma unroll
    for (int nt = 0; nt < 8; nt++) {
        Yb[(r0 + orow + 0) * FH + nt * 16 + m] = f2bf(acc[nt][0] * rsv.x);
        Yb[(r0 + orow + 1) * FH + nt * 16 + m] = f2bf(acc[nt][1] * rsv.y);
        Yb[(r0 + orow + 2) * FH + nt * 16 + m] = f2bf(acc[nt][2] * rsv.z);
        Yb[(r0 + orow + 3) * FH + nt * 16 + m] = f2bf(acc[nt][3] * rsv.w);
    }
}

// ---------------- K3: L2-direct flat-quad gather over bf16 Y -> bf16 H1 ----------------
// Block=(graph, sb). 8 groups x 32 lanes; lane owns 4 bf16 features (ushort4, 8B).
__global__ __launch_bounds__(256) void k_gather(const unsigned short* __restrict__ Yb,
                                                const int* __restrict__ row_ofs,
                                                const int* __restrict__ csr_src,
                                                const int* __restrict__ csr_dst,
                                                const int* __restrict__ seg,
                                                const float* __restrict__ rs_in,
                                                const float* __restrict__ bias,
                                                unsigned short* __restrict__ H) {
    int g  = blockIdx.x;
    int sb = blockIdx.y;   // 0..7
    int tid = threadIdx.x;
    int lane = tid & 31;
    int grp  = tid >> 5;   // 0..7

    __shared__ float rsin_s[NN];   // 2 KB
    for (int i = tid; i < NN; i += 256) rsin_s[i] = rs_in[g * NN + i];
    __syncthreads();

    int sidx = sb * 8 + grp;
    int d0 = seg[g * (NSEG + 1) + sidx], d1 = seg[g * (NSEG + 1) + sidx + 1];
    if (d0 >= d1) return;   // no barriers after this point

    const int* ro = row_ofs + g * 513;
    const ushort4* Yv = (const ushort4*)(Yb + (size_t)g * NN * FH);
    const int* cs = csr_src + (size_t)g * NE;
    const int* cd = csr_dst + (size_t)g * NE;
    int e0 = ro[d0], eEnd = ro[d1];
    float4 bv = ((const float4*)bias)[lane];
    us4v rbn;   // relu(b) in bf16, value for empty rows
    rbn.x = f2bf(fmaxf(bv.x, 0.f)); rbn.y = f2bf(fmaxf(bv.y, 0.f));
    rbn.z = f2bf(fmaxf(bv.z, 0.f)); rbn.w = f2bf(fmaxf(bv.w, 0.f));
    us4v* Hg = (us4v*)(H + (size_t)g * NN * FH) + lane;

    int d = d0;
    float4 acc = make_float4(0.f, 0.f, 0.f, 0.f);
    int e = e0 & ~3;
    int4 S0 = *(const int4*)(cs + e),     D0 = *(const int4*)(cd + e);
    int4 S1 = *(const int4*)(cs + e + 4), D1 = *(const int4*)(cd + e + 4);
    ushort4 y0 = Yv[S0.x * 32 + lane];
    ushort4 y1 = Yv[S0.y * 32 + lane];
    ushort4 y2 = Yv[S0.z * 32 + lane];
    ushort4 y3 = Yv[S0.w * 32 + lane];
    for (; e < eEnd; e += 4) {
        int4 S2 = *(const int4*)(cs + e + 8);   // padded: always safe
        int4 D2 = *(const int4*)(cd + e + 8);
        ushort4 z0 = Yv[S1.x * 32 + lane];
        ushort4 z1 = Yv[S1.y * 32 + lane];
        ushort4 z2 = Yv[S1.z * 32 + lane];
        ushort4 z3 = Yv[S1.w * 32 + lane];
#define STEP(J, DJ, YJ)                                                     \
        {                                                                   \
            int idx = e + (J);                                              \
            bool valid = (idx >= e0) & (idx < eEnd);                        \
            if (valid && (DJ) != d) {                                       \
                float r = rsin_s[d];                                        \
                us4v h;                                                     \
                h.x = f2bf(fmaxf(fmaf(r, acc.x, bv.x), 0.f));               \
                h.y = f2bf(fmaxf(fmaf(r, acc.y, bv.y), 0.f));               \
                h.z = f2bf(fmaxf(fmaf(r, acc.z, bv.z), 0.f));               \
                h.w = f2bf(fmaxf(fmaf(r, acc.w, bv.w), 0.f));               \
                __builtin_nontemporal_store(h, Hg + (size_t)d * 32);        \
                for (int dd = d + 1; dd < (DJ); dd++)                       \
                    __builtin_nontemporal_store(rbn, Hg + (size_t)dd * 32); \
                d = (DJ);                                                   \
                acc = make_float4(0.f, 0.f, 0.f, 0.f);                      \
            }                                                               \
            if (valid) f4acc(acc, bf4_to_f4(YJ));                           \
        }
        STEP(0, D0.x, y0) STEP(1, D0.y, y1) STEP(2, D0.z, y2) STEP(3, D0.w, y3)
#undef STEP
        S0 = S1; D0 = D1; S1 = S2; D1 = D2;
        y0 = z0; y1 = z1; y2 = z2; y3 = z3;
    }
    {   // final flush + trailing empty rows
        float r = rsin_s[d];
        us4v h;
        h.x = f2bf(fmaxf(fmaf(r, acc.x, bv.x), 0.f));
        h.y = f2bf(fmaxf(fmaf(r, acc.y, bv.y), 0.f));
        h.z = f2bf(fmaxf(fmaf(r, acc.z, bv.z), 0.f));
        h.w = f2bf(fmaxf(fmaf(r, acc.w, bv.w), 0.f));
        __builtin_nontemporal_store(h, Hg + (size_t)d * 32);
        for (int dd = d + 1; dd < d1; dd++)
            __builtin_nontemporal_store(rbn, Hg + (size_t)dd * 32);
    }
}

// ---------------- K5: flat-quad gather2 over bf16 Y + node-sum -> partial[g][sb] (fp32) ----------------
__global__ __launch_bounds__(256) void k_gather_mean(const unsigned short* __restrict__ Yb,
                                                     const int* __restrict__ row_ofs,
                                                     const int* __restrict__ csr_src,
                                                     const int* __restrict__ csr_dst,
                                                     const int* __restrict__ seg,
                                                     const float* __restrict__ rs_in,
                                                     const float* __restrict__ bias,
                                                     float* __restrict__ partial) {
    int g  = blockIdx.x;
    int sb = blockIdx.y;
    int tid = threadIdx.x;
    int lane = tid & 31;
    int grp  = tid >> 5;

    __shared__ float rsin_s[NN];     // 2 KB
    __shared__ float4 red[8][32];    // 4 KB
    for (int i = tid; i < NN; i += 256) rsin_s[i] = rs_in[g * NN + i];
    __syncthreads();

    int sidx = sb * 8 + grp;
    int d0 = seg[g * (NSEG + 1) + sidx], d1 = seg[g * (NSEG + 1) + sidx + 1];

    const int* ro = row_ofs + g * 513;
    const ushort4* Yv = (const ushort4*)(Yb + (size_t)g * NN * FH);
    const int* cs = csr_src + (size_t)g * NE;
    const int* cd = csr_dst + (size_t)g * NE;
    float4 bv = ((const float4*)bias)[lane];
    float4 rb;
    rb.x = fmaxf(bv.x, 0.f); rb.y = fmaxf(bv.y, 0.f);
    rb.z = fmaxf(bv.z, 0.f); rb.w = fmaxf(bv.w, 0.f);

    float4 sum = make_float4(0.f, 0.f, 0.f, 0.f);
    if (d0 < d1) {
        int e0 = ro[d0], eEnd = ro[d1];
        int d = d0;
        float4 acc = make_float4(0.f, 0.f, 0.f, 0.f);
        int e = e0 & ~3;
        int4 S0 = *(const int4*)(cs + e),     D0 = *(const int4*)(cd + e);
        int4 S1 = *(const int4*)(cs + e + 4), D1 = *(const int4*)(cd + e + 4);
        ushort4 y0 = Yv[S0.x * 32 + lane];
        ushort4 y1 = Yv[S0.y * 32 + lane];
        ushort4 y2 = Yv[S0.z * 32 + lane];
        ushort4 y3 = Yv[S0.w * 32 + lane];
        for (; e < eEnd; e += 4) {
            int4 S2 = *(const int4*)(cs + e + 8);
            int4 D2 = *(const int4*)(cd + e + 8);
            ushort4 z0 = Yv[S1.x * 32 + lane];
            ushort4 z1 = Yv[S1.y * 32 + lane];
            ushort4 z2 = Yv[S1.z * 32 + lane];
            ushort4 z3 = Yv[S1.w * 32 + lane];
#define STEP(J, DJ, YJ)                                                     \
            {                                                               \
                int idx = e + (J);                                          \
                bool valid = (idx >= e0) & (idx < eEnd);                    \
                if (valid && (DJ) != d) {                                   \
                    float r = rsin_s[d];                                    \
                    sum.x += fmaxf(fmaf(r, acc.x, bv.x), 0.f);              \
                    sum.y += fmaxf(fmaf(r, acc.y, bv.y), 0.f);              \
                    sum.z += fmaxf(fmaf(r, acc.z, bv.z), 0.f);              \
                    sum.w += fmaxf(fmaf(r, acc.w, bv.w), 0.f);              \
                    float gf = (float)((DJ) - d - 1);                       \
                    sum.x += gf * rb.x; sum.y += gf * rb.y;                 \
                    sum.z += gf * rb.z; sum.w += gf * rb.w;                 \
                    d = (DJ);                                               \
                    acc = make_float4(0.f, 0.f, 0.f, 0.f);                  \
                }                                                           \
                if (valid) f4acc(acc, bf4_to_f4(YJ));                       \
            }
            STEP(0, D0.x, y0) STEP(1, D0.y, y1) STEP(2, D0.z, y2) STEP(3, D0.w, y3)
#undef STEP
            S0 = S1; D0 = D1; S1 = S2; D1 = D2;
            y0 = z0; y1 = z1; y2 = z2; y3 = z3;
        }
        {   // final flush + trailing empties
            float r = rsin_s[d];
            sum.x += fmaxf(fmaf(r, acc.x, bv.x), 0.f);
            sum.y += fmaxf(fmaf(r, acc.y, bv.y), 0.f);
            sum.z += fmaxf(fmaf(r, acc.z, bv.z), 0.f);
            sum.w += fmaxf(fmaf(r, acc.w, bv.w), 0.f);
            float gf = (float)(d1 - 1 - d);
            sum.x += gf * rb.x; sum.y += gf * rb.y;
            sum.z += gf * rb.z; sum.w += gf * rb.w;
        }
    }

    red[grp][lane] = sum;
    __syncthreads();
    if (grp == 0) {
        float4 t = red[0][lane];
#pragma unroll
        for (int j = 1; j < 8; j++) f4acc(t, red[j][lane]);
        *(float4*)(partial + (((size_t)g * 8 + sb) * FH) + lane * 4) = t;
    }
}

// ---------------- K6: z = (sum partials)/512 @ Wt + bt; BN eval; relu ----------------
__global__ __launch_bounds__(128) void k_head(const float* __restrict__ partial,
                                              const float* __restrict__ Wt,
                                              const float* __restrict__ bt,
                                              const float* __restrict__ gamma,
                                              const float* __restrict__ beta,
                                              const float* __restrict__ rmean,
                                              const float* __restrict__ rvar,
                                              float* __restrict__ out) {
    int g = blockIdx.x;
    int j = threadIdx.x;
    __shared__ float e[FH];
    float acc8 = 0.f;
#pragma unroll
    for (int q = 0; q < 8; q++) acc8 += partial[((size_t)g * 8 + q) * FH + j];
    e[j] = acc8 * (1.0f / (float)NN);
    __syncthreads();
    float acc = bt[j];
#pragma unroll 8
    for (int k = 0; k < FH; k++) acc += e[k] * Wt[(size_t)k * FH + j];
    float z = gamma[j] * (acc - rmean[j]) * rsqrtf(rvar[j] + BN_EPS) + beta[j];
    out[g * FH + j] = fmaxf(z, 0.f);
}

extern "C" void kernel_launch(void* const* d_in, const int* in_sizes, int n_in,
                              void* d_out, int out_size, void* d_ws, size_t ws_size,
                              hipStream_t stream) {
    const float* feats = (const float*)d_in[0];
    const int*   edges = (const int*)d_in[1];
    const float* W0    = (const float*)d_in[2];
    const float* b0    = (const float*)d_in[3];
    const float* W1    = (const float*)d_in[4];
    const float* b1    = (const float*)d_in[5];
    const float* Wt    = (const float*)d_in[6];
    const float* bt    = (const float*)d_in[7];
    const float* gamma = (const float*)d_in[8];
    const float* beta  = (const float*)d_in[9];
    const float* rmean = (const float*)d_in[10];
    const float* rvar  = (const float*)d_in[11];
    float* out = (float*)d_out;

    // workspace layout
    char* w = (char*)d_ws;
    float* rs_out  = (float*)w;   w += sizeof(float) * NG * NN;
    float* rs_in   = (float*)w;   w += sizeof(float) * NG * NN;
    int*   row_ofs = (int*)w;     w += sizeof(int) * NG * 520;
    int*   seg     = (int*)w;     w += sizeof(int) * NG * (NSEG + 1) + 64;
    int*   csr_src = (int*)w;     w += sizeof(int) * ((size_t)NG * NE + 16);
    int*   csr_dst = (int*)w;     w += sizeof(int) * ((size_t)NG * NE + 16);
    unsigned short* WP = (unsigned short*)w;  w += sizeof(unsigned short) * 4 * 16384; // 128 KB
    unsigned short* Yb  = (unsigned short*)w; w += sizeof(unsigned short) * (size_t)NG * NN * FH; // 16 MB
    unsigned short* H1b = (unsigned short*)w; w += sizeof(unsigned short) * (size_t)NG * NN * FH; // 16 MB
    float* partial = (float*)w;   w += sizeof(float) * NG * 8 * FH;

    unsigned short* WPh0 = WP;
    unsigned short* WPl0 = WP + 16384;
    unsigned short* WPh1 = WP + 32768;
    unsigned short* WPl1 = WP + 49152;

    // K1: build norms + CSR + segments; 2 extra blocks pack W0/W1
    k_build<<<NG + 2, 1024, 0, stream>>>(edges, rs_out, rs_in, row_ofs, csr_src, csr_dst, seg,
                                         W0, W1, WP);

    // K2: x = graph, y = slab -> Y produced on XCD g%8
    k_gemm_f32<<<dim3(NG, 8), 256, 0, stream>>>(feats, WPh0, WPl0, rs_out, Yb);

    k_gather<<<dim3(NG, 8), 256, 0, stream>>>(Yb, row_ofs, csr_src, csr_dst, seg, rs_in, b0, H1b);

    k_gemm_bf16<<<dim3(NG, 8), 256, 0, stream>>>(H1b, WPh1, WPl1, rs_out, Yb);

    k_gather_mean<<<dim3(NG, 8), 256, 0, stream>>>(Yb, row_ofs, csr_src, csr_dst, seg, rs_in, b1, partial);

    k_head<<<NG, 128, 0, stream>>>(partial, Wt, bt, gamma, beta, rmean, rvar, out);

    (void)in_sizes; (void)n_in; (void)out_size; (void)ws_size;
}

// Round 12
// 194.024 us; speedup vs baseline: 1.1562x; 1.0296x over previous
//
#include <hip/hip_runtime.h>
#include <hip/hip_bf16.h>

#define NN 512      // nodes per graph
#define NE 8192     // edges per graph
#define NG 128      // graphs (B*G)
#define FH 128      // feature/hidden dim
#define NSEG 64     // segments: 8 per 64-row slab, edge-balanced within slab
#define BN_EPS 1e-5f

typedef __attribute__((ext_vector_type(8))) short s8v;            // 8 bf16 = 4 VGPRs
typedef __attribute__((ext_vector_type(4))) float f4v;            // MFMA C/D
typedef __attribute__((ext_vector_type(4))) unsigned short us4v;  // native ushort4

__device__ inline void f4acc(float4& a, const float4& b) {
    a.x += b.x; a.y += b.y; a.z += b.z; a.w += b.w;
}

__device__ inline unsigned short f2bf(float x) {   // RNE fp32 -> bf16 bits
    unsigned u = __float_as_uint(x);
    unsigned r = (u + 0x7fffu + ((u >> 16) & 1u)) >> 16;
    return (unsigned short)r;
}
__device__ inline float bf2f(unsigned short h) { return __uint_as_float(((unsigned)h) << 16); }
__device__ inline float4 bf4_to_f4(const ushort4& v) {
    return make_float4(bf2f(v.x), bf2f(v.y), bf2f(v.z), bf2f(v.w));
}

// ---------------- K1: degrees + norms + CSR (src+dst) + slab-aligned segments; packW ----------------
__global__ __launch_bounds__(1024) void k_build(const int* __restrict__ edges,
                                                float* __restrict__ rs_out,
                                                float* __restrict__ rs_in,
                                                int* __restrict__ row_ofs,
                                                int* __restrict__ csr_src,
                                                int* __restrict__ csr_dst,
                                                int* __restrict__ seg,
                                                const float* __restrict__ W0,
                                                const float* __restrict__ W1,
                                                unsigned short* __restrict__ WP) {
    int g = blockIdx.x;
    int tid = threadIdx.x;

    if (g >= NG) {
        int which = g - NG;
        const float* W = which ? W1 : W0;
        for (int task = tid; task < 2048; task += 1024) {
            int t = task >> 6;            // 0..31  (nt*4+kk)
            int lane = task & 63;
            int nt = t >> 2, kk = t & 3;
            int n = nt * 16 + (lane & 15);
            int k0 = kk * 32 + (lane >> 4) * 8;
            unsigned short* dh = WP + ((size_t)which * 2 + 0) * 16384 + ((size_t)t * 64 + lane) * 8;
            unsigned short* dl = WP + ((size_t)which * 2 + 1) * 16384 + ((size_t)t * 64 + lane) * 8;
#pragma unroll
            for (int j = 0; j < 8; j++) {
                float v = W[(size_t)(k0 + j) * FH + n];
                unsigned short h = f2bf(v);
                dh[j] = h;
                dl[j] = f2bf(v - bf2f(h));
            }
        }
        return;
    }

    const int* src = edges + (size_t)g * 2 * NE;
    const int* dst = src + NE;

    __shared__ int degO[NN], degI[NN];
    __shared__ int scanA[NN], scanB[NN];
    __shared__ int fill[NN];
    __shared__ int csr_lds[NE];          // 32 KB
    __shared__ int dst_lds[NE];          // 32 KB

    for (int i = tid; i < NN; i += 1024) { degO[i] = 0; degI[i] = 0; }
    __syncthreads();
    for (int u = tid; u < NE / 4; u += 1024) {
        int4 s = ((const int4*)src)[u];
        int4 d = ((const int4*)dst)[u];
        atomicAdd(&degO[s.x], 1); atomicAdd(&degO[s.y], 1);
        atomicAdd(&degO[s.z], 1); atomicAdd(&degO[s.w], 1);
        atomicAdd(&degI[d.x], 1); atomicAdd(&degI[d.y], 1);
        atomicAdd(&degI[d.z], 1); atomicAdd(&degI[d.w], 1);
    }
    __syncthreads();
    for (int i = tid; i < NN; i += 1024) {
        int dO = degO[i], dI = degI[i];
        rs_out[g * NN + i] = rsqrtf((float)max(dO, 1));
        rs_in [g * NN + i] = rsqrtf((float)max(dI, 1));
        scanA[i] = dI;
    }
    __syncthreads();
    int* sA = scanA; int* sB = scanB;
    for (int off = 1; off < NN; off <<= 1) {
        for (int i = tid; i < NN; i += 1024) {
            int v = sA[i];
            if (i >= off) v += sA[i - off];
            sB[i] = v;
        }
        __syncthreads();
        int* t = sA; sA = sB; sB = t;
    }
    for (int i = tid; i < NN; i += 1024) {
        int excl = (i == 0) ? 0 : sA[i - 1];
        fill[i] = excl;
        row_ofs[g * 513 + i] = excl;
    }
    if (tid == 0) row_ofs[g * 513 + NN] = sA[NN - 1];
    // slab-aligned, edge-balanced-in-slab segments: 8 per 64-row slab.
    // seg[sb*8] == 64*sb by construction.
    if (tid < NSEG) {
        int sb = tid >> 3, j = tid & 7;
        int base_row = sb * 64;
        int cumB = (base_row == 0) ? 0 : sA[base_row - 1];
        int slabE = sA[base_row + 63] - cumB;
        int target = cumB + (j * slabE) / 8;
        int lo = base_row, hi = base_row + 64;
        while (lo < hi) {
            int mid = (lo + hi) >> 1;
            int ex = (mid == 0) ? 0 : sA[mid - 1];
            if (ex >= target) hi = mid; else lo = mid + 1;
        }
        seg[g * (NSEG + 1) + tid] = lo;
    }
    if (tid == 0) seg[g * (NSEG + 1) + NSEG] = NN;
    __syncthreads();
    for (int u = tid; u < NE / 4; u += 1024) {
        int4 s = ((const int4*)src)[u];
        int4 d = ((const int4*)dst)[u];
        int p0 = atomicAdd(&fill[d.x], 1); csr_lds[p0] = s.x; dst_lds[p0] = d.x;
        int p1 = atomicAdd(&fill[d.y], 1); csr_lds[p1] = s.y; dst_lds[p1] = d.y;
        int p2 = atomicAdd(&fill[d.z], 1); csr_lds[p2] = s.z; dst_lds[p2] = d.z;
        int p3 = atomicAdd(&fill[d.w], 1); csr_lds[p3] = s.w; dst_lds[p3] = d.w;
    }
    __syncthreads();
    for (int u = tid; u < NE / 4; u += 1024) {
        ((int4*)(csr_src + (size_t)g * NE))[u] = ((const int4*)csr_lds)[u];
        ((int4*)(csr_dst + (size_t)g * NE))[u] = ((const int4*)dst_lds)[u];
    }
    if (g == NG - 1 && tid < 16) {
        csr_src[(size_t)NG * NE + tid] = 0;
        csr_dst[(size_t)NG * NE + tid] = 0;
    }
}

// ---------------- K2: Yb(bf16) = (feats(fp32) @ W0) * rs  (hi/lo split, 3 MFMA) ----------------
#define XPITCH 136
__global__ __launch_bounds__(256) void k_gemm_f32(const float* __restrict__ X,
                                                  const unsigned short* __restrict__ WPh,
                                                  const unsigned short* __restrict__ WPl,
                                                  const float* __restrict__ rs,
                                                  unsigned short* __restrict__ Yb) {
    __shared__ unsigned short xh[64 * XPITCH];   // 17 KB
    __shared__ unsigned short xl[64 * XPITCH];   // 17 KB
    int tid = threadIdx.x;
    size_t r0 = (size_t)blockIdx.x * NN + (size_t)blockIdx.y * 64;

    const float4* Xv = (const float4*)(X + r0 * FH);
#pragma unroll
    for (int i = 0; i < 8; i++) {
        int u = tid + i * 256;                 // 2048 float4 = 64x128
        int row = u >> 5, c4 = (u & 31) * 4;
        float4 v = Xv[u];
        int off = row * XPITCH + c4;
        unsigned short h0 = f2bf(v.x), h1 = f2bf(v.y), h2 = f2bf(v.z), h3 = f2bf(v.w);
        xh[off + 0] = h0; xh[off + 1] = h1; xh[off + 2] = h2; xh[off + 3] = h3;
        xl[off + 0] = f2bf(v.x - bf2f(h0));
        xl[off + 1] = f2bf(v.y - bf2f(h1));
        xl[off + 2] = f2bf(v.z - bf2f(h2));
        xl[off + 3] = f2bf(v.w - bf2f(h3));
    }
    __syncthreads();

    int lane = tid & 63, w = tid >> 6;
    int quad = lane >> 4, m = lane & 15;
    int arow = w * 16 + m;

    f4v acc[8];
#pragma unroll
    for (int nt = 0; nt < 8; nt++) acc[nt] = (f4v){0.f, 0.f, 0.f, 0.f};

#pragma unroll
    for (int kk = 0; kk < 4; kk++) {
        s8v ah = *(const s8v*)&xh[arow * XPITCH + kk * 32 + quad * 8];
        s8v al = *(const s8v*)&xl[arow * XPITCH + kk * 32 + quad * 8];
#pragma unroll
        for (int nt = 0; nt < 8; nt++) {
            s8v bh = *(const s8v*)(WPh + ((size_t)(nt * 4 + kk) * 64 + lane) * 8);
            s8v bl = *(const s8v*)(WPl + ((size_t)(nt * 4 + kk) * 64 + lane) * 8);
            acc[nt] = __builtin_amdgcn_mfma_f32_16x16x32_bf16(ah, bh, acc[nt], 0, 0, 0);
            acc[nt] = __builtin_amdgcn_mfma_f32_16x16x32_bf16(al, bh, acc[nt], 0, 0, 0);
            acc[nt] = __builtin_amdgcn_mfma_f32_16x16x32_bf16(ah, bl, acc[nt], 0, 0, 0);
        }
    }

    int orow = w * 16 + quad * 4;
    float4 rsv = *(const float4*)(rs + r0 + orow);
#pragma unroll
    for (int nt = 0; nt < 8; nt++) {
        Yb[(r0 + orow + 0) * FH + nt * 16 + m] = f2bf(acc[nt][0] * rsv.x);
        Yb[(r0 + orow + 1) * FH + nt * 16 + m] = f2bf(acc[nt][1] * rsv.y);
        Yb[(r0 + orow + 2) * FH + nt * 16 + m] = f2bf(acc[nt][2] * rsv.z);
        Yb[(r0 + orow + 3) * FH + nt * 16 + m] = f2bf(acc[nt][3] * rsv.w);
    }
}

// ---------------- K3: FUSED gather(conv1 epilogue) -> LDS h-tile -> bf16 MFMA gemm2 -> Y2 ----------------
// Block (g, sb) owns slab rows [64sb, 64sb+64). Gather phase: 8 groups x 32 lanes
// walk slab-aligned segments, writing bf16 h rows into LDS. Gemm phase: standard
// 2-MFMA bf16 tile from LDS, scaled by rs_out, written to Y2.
__global__ __launch_bounds__(256) void k_fused(const unsigned short* __restrict__ Y1,
                                               const int* __restrict__ row_ofs,
                                               const int* __restrict__ csr_src,
                                               const int* __restrict__ csr_dst,
                                               const int* __restrict__ seg,
                                               const float* __restrict__ rs_in,
                                               const float* __restrict__ rs_out,
                                               const float* __restrict__ bias,
                                               const unsigned short* __restrict__ WPh,
                                               const unsigned short* __restrict__ WPl,
                                               unsigned short* __restrict__ Y2) {
    int g  = blockIdx.x;
    int sb = blockIdx.y;   // 0..7
    int tid = threadIdx.x;
    int lane = tid & 31;
    int grp  = tid >> 5;   // 0..7
    int base = sb * 64;

    __shared__ unsigned short hs[64 * XPITCH];   // 17 KB bf16 h-tile
    __shared__ float rsin_s[64];                 // slab rs_in

    if (tid < 64) rsin_s[tid] = rs_in[g * NN + base + tid];
    __syncthreads();

    int sidx = sb * 8 + grp;
    int d0 = seg[g * (NSEG + 1) + sidx], d1 = seg[g * (NSEG + 1) + sidx + 1];

    {   // ---- gather phase ----
        const int* ro = row_ofs + g * 513;
        const ushort4* Yv = (const ushort4*)(Y1 + (size_t)g * NN * FH);
        const int* cs = csr_src + (size_t)g * NE;
        const int* cd = csr_dst + (size_t)g * NE;
        float4 bv = ((const float4*)bias)[lane];
        us4v rbn;
        rbn.x = f2bf(fmaxf(bv.x, 0.f)); rbn.y = f2bf(fmaxf(bv.y, 0.f));
        rbn.z = f2bf(fmaxf(bv.z, 0.f)); rbn.w = f2bf(fmaxf(bv.w, 0.f));

        if (d0 < d1) {
            int e0 = ro[d0], eEnd = ro[d1];
            int d = d0;
            float4 acc = make_float4(0.f, 0.f, 0.f, 0.f);
            int e = e0 & ~3;
            int4 S0 = *(const int4*)(cs + e),     D0 = *(const int4*)(cd + e);
            int4 S1 = *(const int4*)(cs + e + 4), D1 = *(const int4*)(cd + e + 4);
            ushort4 y0 = Yv[S0.x * 32 + lane];
            ushort4 y1 = Yv[S0.y * 32 + lane];
            ushort4 y2 = Yv[S0.z * 32 + lane];
            ushort4 y3 = Yv[S0.w * 32 + lane];
            for (; e < eEnd; e += 4) {
                int4 S2 = *(const int4*)(cs + e + 8);   // padded: safe
                int4 D2 = *(const int4*)(cd + e + 8);
                ushort4 z0 = Yv[S1.x * 32 + lane];
                ushort4 z1 = Yv[S1.y * 32 + lane];
                ushort4 z2 = Yv[S1.z * 32 + lane];
                ushort4 z3 = Yv[S1.w * 32 + lane];
#define STEP(J, DJ, YJ)                                                     \
                {                                                           \
                    int idx = e + (J);                                      \
                    bool valid = (idx >= e0) & (idx < eEnd);                \
                    if (valid && (DJ) != d) {                               \
                        float r = rsin_s[d - base];                         \
                        us4v h;                                             \
                        h.x = f2bf(fmaxf(fmaf(r, acc.x, bv.x), 0.f));       \
                        h.y = f2bf(fmaxf(fmaf(r, acc.y, bv.y), 0.f));       \
                        h.z = f2bf(fmaxf(fmaf(r, acc.z, bv.z), 0.f));       \
                        h.w = f2bf(fmaxf(fmaf(r, acc.w, bv.w), 0.f));       \
                        *(us4v*)&hs[(d - base) * XPITCH + lane * 4] = h;    \
                        for (int dd = d + 1; dd < (DJ); dd++)               \
                            *(us4v*)&hs[(dd - base) * XPITCH + lane * 4] = rbn; \
                        d = (DJ);                                           \
                        acc = make_float4(0.f, 0.f, 0.f, 0.f);              \
                    }                                                       \
                    if (valid) f4acc(acc, bf4_to_f4(YJ));                   \
                }
                STEP(0, D0.x, y0) STEP(1, D0.y, y1) STEP(2, D0.z, y2) STEP(3, D0.w, y3)
#undef STEP
                S0 = S1; D0 = D1; S1 = S2; D1 = D2;
                y0 = z0; y1 = z1; y2 = z2; y3 = z3;
            }
            {   // final flush + trailing empty rows
                float r = rsin_s[d - base];
                us4v h;
                h.x = f2bf(fmaxf(fmaf(r, acc.x, bv.x), 0.f));
                h.y = f2bf(fmaxf(fmaf(r, acc.y, bv.y), 0.f));
                h.z = f2bf(fmaxf(fmaf(r, acc.z, bv.z), 0.f));
                h.w = f2bf(fmaxf(fmaf(r, acc.w, bv.w), 0.f));
                *(us4v*)&hs[(d - base) * XPITCH + lane * 4] = h;
                for (int dd = d + 1; dd < d1; dd++)
                    *(us4v*)&hs[(dd - base) * XPITCH + lane * 4] = rbn;
            }
        }
    }
    __syncthreads();

    // ---- gemm phase: Y2[slab] = (h @ W1) * rs_out ----
    int lane64 = tid & 63, w = tid >> 6;
    int quad = lane64 >> 4, m = lane64 & 15;
    int arow = w * 16 + m;
    size_t r0 = (size_t)g * NN + base;

    f4v acc[8];
#pragma unroll
    for (int nt = 0; nt < 8; nt++) acc[nt] = (f4v){0.f, 0.f, 0.f, 0.f};

#pragma unroll
    for (int kk = 0; kk < 4; kk++) {
        s8v ah = *(const s8v*)&hs[arow * XPITCH + kk * 32 + quad * 8];
#pragma unroll
        for (int nt = 0; nt < 8; nt++) {
            s8v bh = *(const s8v*)(WPh + ((size_t)(nt * 4 + kk) * 64 + lane64) * 8);
            s8v bl = *(const s8v*)(WPl + ((size_t)(nt * 4 + kk) * 64 + lane64) * 8);
            acc[nt] = __builtin_amdgcn_mfma_f32_16x16x32_bf16(ah, bh, acc[nt], 0, 0, 0);
            acc[nt] = __builtin_amdgcn_mfma_f32_16x16x32_bf16(ah, bl, acc[nt], 0, 0, 0);
        }
    }

    int orow = w * 16 + quad * 4;
    float4 rsv = *(const float4*)(rs_out + r0 + orow);
#pragma unroll
    for (int nt = 0; nt < 8; nt++) {
        Y2[(r0 + orow + 0) * FH + nt * 16 + m] = f2bf(acc[nt][0] * rsv.x);
        Y2[(r0 + orow + 1) * FH + nt * 16 + m] = f2bf(acc[nt][1] * rsv.y);
        Y2[(r0 + orow + 2) * FH + nt * 16 + m] = f2bf(acc[nt][2] * rsv.z);
        Y2[(r0 + orow + 3) * FH + nt * 16 + m] = f2bf(acc[nt][3] * rsv.w);
    }
}

// ---------------- K5: flat-quad gather2 over bf16 Y2 + node-sum -> partial[g][sb] ----------------
__global__ __launch_bounds__(256) void k_gather_mean(const unsigned short* __restrict__ Yb,
                                                     const int* __restrict__ row_ofs,
                                                     const int* __restrict__ csr_src,
                                                     const int* __restrict__ csr_dst,
                                                     const int* __restrict__ seg,
                                                     const float* __restrict__ rs_in,
                                                     const float* __restrict__ bias,
                                                     float* __restrict__ partial) {
    int g  = blockIdx.x;
    int sb = blockIdx.y;
    int tid = threadIdx.x;
    int lane = tid & 31;
    int grp  = tid >> 5;

    __shared__ float rsin_s[NN];     // 2 KB
    __shared__ float4 red[8][32];    // 4 KB
    for (int i = tid; i < NN; i += 256) rsin_s[i] = rs_in[g * NN + i];
    __syncthreads();

    int sidx = sb * 8 + grp;
    int d0 = seg[g * (NSEG + 1) + sidx], d1 = seg[g * (NSEG + 1) + sidx + 1];

    const int* ro = row_ofs + g * 513;
    const ushort4* Yv = (const ushort4*)(Yb + (size_t)g * NN * FH);
    const int* cs = csr_src + (size_t)g * NE;
    const int* cd = csr_dst + (size_t)g * NE;
    float4 bv = ((const float4*)bias)[lane];
    float4 rb;
    rb.x = fmaxf(bv.x, 0.f); rb.y = fmaxf(bv.y, 0.f);
    rb.z = fmaxf(bv.z, 0.f); rb.w = fmaxf(bv.w, 0.f);

    float4 sum = make_float4(0.f, 0.f, 0.f, 0.f);
    if (d0 < d1) {
        int e0 = ro[d0], eEnd = ro[d1];
        int d = d0;
        float4 acc = make_float4(0.f, 0.f, 0.f, 0.f);
        int e = e0 & ~3;
        int4 S0 = *(const int4*)(cs + e),     D0 = *(const int4*)(cd + e);
        int4 S1 = *(const int4*)(cs + e + 4), D1 = *(const int4*)(cd + e + 4);
        ushort4 y0 = Yv[S0.x * 32 + lane];
        ushort4 y1 = Yv[S0.y * 32 + lane];
        ushort4 y2 = Yv[S0.z * 32 + lane];
        ushort4 y3 = Yv[S0.w * 32 + lane];
        for (; e < eEnd; e += 4) {
            int4 S2 = *(const int4*)(cs + e + 8);
            int4 D2 = *(const int4*)(cd + e + 8);
            ushort4 z0 = Yv[S1.x * 32 + lane];
            ushort4 z1 = Yv[S1.y * 32 + lane];
            ushort4 z2 = Yv[S1.z * 32 + lane];
            ushort4 z3 = Yv[S1.w * 32 + lane];
#define STEP(J, DJ, YJ)                                                     \
            {                                                               \
                int idx = e + (J);                                          \
                bool valid = (idx >= e0) & (idx < eEnd);                    \
                if (valid && (DJ) != d) {                                   \
                    float r = rsin_s[d];                                    \
                    sum.x += fmaxf(fmaf(r, acc.x, bv.x), 0.f);              \
                    sum.y += fmaxf(fmaf(r, acc.y, bv.y), 0.f);              \
                    sum.z += fmaxf(fmaf(r, acc.z, bv.z), 0.f);              \
                    sum.w += fmaxf(fmaf(r, acc.w, bv.w), 0.f);              \
                    float gf = (float)((DJ) - d - 1);                       \
                    sum.x += gf * rb.x; sum.y += gf * rb.y;                 \
                    sum.z += gf * rb.z; sum.w += gf * rb.w;                 \
                    d = (DJ);                                               \
                    acc = make_float4(0.f, 0.f, 0.f, 0.f);                  \
                }                                                           \
                if (valid) f4acc(acc, bf4_to_f4(YJ));                       \
            }
            STEP(0, D0.x, y0) STEP(1, D0.y, y1) STEP(2, D0.z, y2) STEP(3, D0.w, y3)
#undef STEP
            S0 = S1; D0 = D1; S1 = S2; D1 = D2;
            y0 = z0; y1 = z1; y2 = z2; y3 = z3;
        }
        {   // final flush + trailing empties
            float r = rsin_s[d];
            sum.x += fmaxf(fmaf(r, acc.x, bv.x), 0.f);
            sum.y += fmaxf(fmaf(r, acc.y, bv.y), 0.f);
            sum.z += fmaxf(fmaf(r, acc.z, bv.z), 0.f);
            sum.w += fmaxf(fmaf(r, acc.w, bv.w), 0.f);
            float gf = (float)(d1 - 1 - d);
            sum.x += gf * rb.x; sum.y += gf * rb.y;
            sum.z += gf * rb.z; sum.w += gf * rb.w;
        }
    }

    red[grp][lane] = sum;
    __syncthreads();
    if (grp == 0) {
        float4 t = red[0][lane];
#pragma unroll
        for (int j = 1; j < 8; j++) f4acc(t, red[j][lane]);
        *(float4*)(partial + (((size_t)g * 8 + sb) * FH) + lane * 4) = t;
    }
}

// ---------------- K6: z = (sum partials)/512 @ Wt + bt; BN eval; relu ----------------
__global__ __launch_bounds__(128) void k_head(const float* __restrict__ partial,
                                              const float* __restrict__ Wt,
                                              const float* __restrict__ bt,
                                              const float* __restrict__ gamma,
                                              const float* __restrict__ beta,
                                              const float* __restrict__ rmean,
                                              const float* __restrict__ rvar,
                                              float* __restrict__ out) {
    int g = blockIdx.x;
    int j = threadIdx.x;
    __shared__ float e[FH];
    float acc8 = 0.f;
#pragma unroll
    for (int q = 0; q < 8; q++) acc8 += partial[((size_t)g * 8 + q) * FH + j];
    e[j] = acc8 * (1.0f / (float)NN);
    __syncthreads();
    float acc = bt[j];
#pragma unroll 8
    for (int k = 0; k < FH; k++) acc += e[k] * Wt[(size_t)k * FH + j];
    float z = gamma[j] * (acc - rmean[j]) * rsqrtf(rvar[j] + BN_EPS) + beta[j];
    out[g * FH + j] = fmaxf(z, 0.f);
}

extern "C" void kernel_launch(void* const* d_in, const int* in_sizes, int n_in,
                              void* d_out, int out_size, void* d_ws, size_t ws_size,
                              hipStream_t stream) {
    const float* feats = (const float*)d_in[0];
    const int*   edges = (const int*)d_in[1];
    const float* W0    = (const float*)d_in[2];
    const float* b0    = (const float*)d_in[3];
    const float* W1    = (const float*)d_in[4];
    const float* b1    = (const float*)d_in[5];
    const float* Wt    = (const float*)d_in[6];
    const float* bt    = (const float*)d_in[7];
    const float* gamma = (const float*)d_in[8];
    const float* beta  = (const float*)d_in[9];
    const float* rmean = (const float*)d_in[10];
    const float* rvar  = (const float*)d_in[11];
    float* out = (float*)d_out;

    // workspace layout
    char* w = (char*)d_ws;
    float* rs_out  = (float*)w;   w += sizeof(float) * NG * NN;
    float* rs_in   = (float*)w;   w += sizeof(float) * NG * NN;
    int*   row_ofs = (int*)w;     w += sizeof(int) * NG * 520;
    int*   seg     = (int*)w;     w += sizeof(int) * NG * (NSEG + 1) + 64;
    int*   csr_src = (int*)w;     w += sizeof(int) * ((size_t)NG * NE + 16);
    int*   csr_dst = (int*)w;     w += sizeof(int) * ((size_t)NG * NE + 16);
    unsigned short* WP = (unsigned short*)w;  w += sizeof(unsigned short) * 4 * 16384; // 128 KB
    unsigned short* Y1 = (unsigned short*)w;  w += sizeof(unsigned short) * (size_t)NG * NN * FH; // 16 MB
    unsigned short* Y2 = (unsigned short*)w;  w += sizeof(unsigned short) * (size_t)NG * NN * FH; // 16 MB
    float* partial = (float*)w;   w += sizeof(float) * NG * 8 * FH;

    unsigned short* WPh0 = WP;
    unsigned short* WPl0 = WP + 16384;
    unsigned short* WPh1 = WP + 32768;
    unsigned short* WPl1 = WP + 49152;

    // K1: build norms + CSR + slab-aligned segments; 2 extra blocks pack W0/W1
    k_build<<<NG + 2, 1024, 0, stream>>>(edges, rs_out, rs_in, row_ofs, csr_src, csr_dst, seg,
                                         W0, W1, WP);

    // K2: conv1 gemm (feats -> Y1), XCD = g%8
    k_gemm_f32<<<dim3(NG, 8), 256, 0, stream>>>(feats, WPh0, WPl0, rs_out, Y1);

    // K3: fused conv1-aggregate + conv2-gemm (Y1 -> Y2), no H1 intermediate
    k_fused<<<dim3(NG, 8), 256, 0, stream>>>(Y1, row_ofs, csr_src, csr_dst, seg,
                                             rs_in, rs_out, b0, WPh1, WPl1, Y2);

    // K4: conv2 aggregate + node-mean partials
    k_gather_mean<<<dim3(NG, 8), 256, 0, stream>>>(Y2, row_ofs, csr_src, csr_dst, seg, rs_in, b1, partial);

    // K5: head
    k_head<<<NG, 128, 0, stream>>>(partial, Wt, bt, gamma, beta, rmean, rvar, out);

    (void)in_sizes; (void)n_in; (void)out_size; (void)ws_size;
}